// Round 2
// baseline (4348.004 us; speedup 1.0000x reference)
//
#include <hip/hip_runtime.h>
#include <math.h>

#define TT 2048      // B*S tokens
#define BB 2
#define SS 1024
#define DD 768
#define HH 12
#define FF 3072
#define EE 8
#define VV 32000
#define NLAYER 2
#define QBLK 8

// ---------------- embedding: x = emb[tok] + pos ----------------
__global__ __launch_bounds__(256) void k_embed(const int* __restrict__ tok,
    const float* __restrict__ emb, const float* __restrict__ pos,
    float* __restrict__ x) {
  int t = blockIdx.x;
  int s = t & (SS - 1);
  int tk = tok[t];
  const float* er = emb + (size_t)tk * DD;
  const float* pr = pos + (size_t)s * DD;
  float* xr = x + (size_t)t * DD;
  for (int d = threadIdx.x; d < DD; d += 256)
    xr[d] = er[d] + pr[d];
}

// ---------------- rmsnorm (row per block, 256 thr) ----------------
__global__ __launch_bounds__(256) void k_rmsnorm(const float* __restrict__ x,
    const float* __restrict__ w, float* __restrict__ out) {
  int t = blockIdx.x;
  const float* xr = x + (size_t)t * DD;
  int tid = threadIdx.x;
  float v0 = xr[tid], v1 = xr[tid + 256], v2 = xr[tid + 512];
  float ss = v0 * v0 + v1 * v1 + v2 * v2;
  for (int off = 32; off > 0; off >>= 1) ss += __shfl_down(ss, off, 64);
  __shared__ float ps[4];
  int wid = tid >> 6, lane = tid & 63;
  if (lane == 0) ps[wid] = ss;
  __syncthreads();
  float r = rsqrtf((ps[0] + ps[1] + ps[2] + ps[3]) * (1.0f / DD) + 1e-6f);
  float* orow = out + (size_t)t * DD;
  orow[tid]       = v0 * r * w[tid];
  orow[tid + 256] = v1 * r * w[tid + 256];
  orow[tid + 512] = v2 * r * w[tid + 512];
}

// ---------------- generic 64x64 NN GEMM: C = A @ B [+bias][+=dest] --------
template<bool BIAS, bool ADD_DEST>
__global__ __launch_bounds__(256) void k_gemm_nn(const float* __restrict__ A,
    const float* __restrict__ Bw, const float* __restrict__ bias,
    float* __restrict__ C, int M, int N, int Kd) {
  __shared__ float As[64][17];
  __shared__ float Bs[16][68];
  int tid = threadIdx.x;
  int tx = tid & 15, ty = tid >> 4;
  int n0 = blockIdx.x * 64, m0 = blockIdx.y * 64;
  int ra = tid >> 2, ka0 = (tid & 3) * 4;
  int kb = tid >> 4, nb0 = (tid & 15) * 4;
  float acc[4][4] = {};
  for (int k0 = 0; k0 < Kd; k0 += 16) {
    float4 av = *(const float4*)(A + (size_t)(m0 + ra) * Kd + k0 + ka0);
    As[ra][ka0 + 0] = av.x; As[ra][ka0 + 1] = av.y;
    As[ra][ka0 + 2] = av.z; As[ra][ka0 + 3] = av.w;
    float4 bv = *(const float4*)(Bw + (size_t)(k0 + kb) * N + n0 + nb0);
    Bs[kb][nb0 + 0] = bv.x; Bs[kb][nb0 + 1] = bv.y;
    Bs[kb][nb0 + 2] = bv.z; Bs[kb][nb0 + 3] = bv.w;
    __syncthreads();
#pragma unroll
    for (int kk = 0; kk < 16; kk++) {
      float a[4], b[4];
#pragma unroll
      for (int i = 0; i < 4; i++) a[i] = As[ty * 4 + i][kk];
#pragma unroll
      for (int j = 0; j < 4; j++) b[j] = Bs[kk][tx * 4 + j];
#pragma unroll
      for (int i = 0; i < 4; i++) {
#pragma unroll
        for (int j = 0; j < 4; j++) acc[i][j] = fmaf(a[i], b[j], acc[i][j]);
      }
    }
    __syncthreads();
  }
#pragma unroll
  for (int i = 0; i < 4; i++) {
    int m = m0 + ty * 4 + i;
    float* crow = C + (size_t)m * N;
#pragma unroll
    for (int j = 0; j < 4; j++) {
      int n = n0 + tx * 4 + j;
      float vv = acc[i][j];
      if (BIAS) vv += bias[n];
      if (ADD_DEST) vv += crow[n];
      crow[n] = vv;
    }
  }
}

// ---------------- attention: QBLK query rows per block ----------------
__global__ __launch_bounds__(256) void k_attn(const float* __restrict__ q,
    const float* __restrict__ k, const float* __restrict__ v, float* __restrict__ ao) {
  int b = blockIdx.z, hh = blockIdx.y, q0 = blockIdx.x * QBLK;
  __shared__ float qs[QBLK][64];
  __shared__ float sc[QBLK][SS];
  __shared__ float red[QBLK][8];
  int tid = threadIdx.x;
  const size_t hoff = (size_t)b * SS * DD + (size_t)hh * 64;
  for (int i = tid; i < QBLK * 64; i += 256) {
    int qi = i >> 6, d = i & 63;
    qs[qi][d] = q[hoff + (size_t)(q0 + qi) * DD + d];
  }
  __syncthreads();
  int kmax = q0 + QBLK;
  // phase 1: scores
  for (int j = tid; j < kmax; j += 256) {
    const float* kr = k + hoff + (size_t)j * DD;
    float p[QBLK];
#pragma unroll
    for (int qi = 0; qi < QBLK; qi++) p[qi] = 0.f;
#pragma unroll 4
    for (int c = 0; c < 16; c++) {
      float4 kv = *(const float4*)(kr + c * 4);
#pragma unroll
      for (int qi = 0; qi < QBLK; qi++)
        p[qi] += qs[qi][c * 4] * kv.x + qs[qi][c * 4 + 1] * kv.y +
                 qs[qi][c * 4 + 2] * kv.z + qs[qi][c * 4 + 3] * kv.w;
    }
#pragma unroll
    for (int qi = 0; qi < QBLK; qi++)
      sc[qi][j] = (j <= q0 + qi) ? p[qi] * 0.125f : -1e30f;
  }
  __syncthreads();
  int wid = tid >> 6, lane = tid & 63;
  // phase 2a: row maxes
#pragma unroll
  for (int qi = 0; qi < QBLK; qi++) {
    float mx = -1e30f;
    for (int j = tid; j < kmax; j += 256) mx = fmaxf(mx, sc[qi][j]);
    for (int off = 32; off > 0; off >>= 1) mx = fmaxf(mx, __shfl_down(mx, off, 64));
    if (lane == 0) red[qi][wid] = mx;
  }
  __syncthreads();
  // phase 2b: exp + sums (unnormalized probs left in sc)
#pragma unroll
  for (int qi = 0; qi < QBLK; qi++) {
    float mx = fmaxf(fmaxf(red[qi][0], red[qi][1]), fmaxf(red[qi][2], red[qi][3]));
    float s = 0.f;
    for (int j = tid; j < kmax; j += 256) {
      float e = __expf(sc[qi][j] - mx);
      sc[qi][j] = e;
      s += e;
    }
    for (int off = 32; off > 0; off >>= 1) s += __shfl_down(s, off, 64);
    if (lane == 0) red[qi][4 + wid] = s;
  }
  __syncthreads();
  // phase 3: out = probs @ V   (wave g handles rows g, g+4; lane owns dim d)
  int d = tid & 63, g = tid >> 6;
  for (int qi = g; qi < QBLK; qi += 4) {
    float inv = 1.f / (red[qi][4] + red[qi][5] + red[qi][6] + red[qi][7]);
    float acc = 0.f;
    int jend = q0 + qi + 1;
    const float* vp = v + hoff + d;
    for (int j = 0; j < jend; j++) acc = fmaf(sc[qi][j], vp[(size_t)j * DD], acc);
    ao[hoff + (size_t)(q0 + qi) * DD + d] = acc * inv;
  }
}

// ---------------- gate logits ----------------
__global__ __launch_bounds__(256) void k_gate(const float* __restrict__ h,
    const float* __restrict__ gw, const float* __restrict__ gb,
    float* __restrict__ glog) {
  __shared__ float hr[DD];
  int t = blockIdx.x;
  for (int d = threadIdx.x; d < DD; d += 256) hr[d] = h[(size_t)t * DD + d];
  __syncthreads();
  int e = threadIdx.x >> 5, j = threadIdx.x & 31;
  float s = 0.f;
  for (int d = j; d < DD; d += 32) s += hr[d] * gw[d * EE + e];
  for (int off = 16; off > 0; off >>= 1) s += __shfl_down(s, off, 32);
  if (j == 0) glog[t * EE + e] = s + gb[e];
}

// ---------------- router ----------------
__global__ void k_zero(int* counts, int* cursor) {
  int i = threadIdx.x;
  if (i < EE) { counts[i] = 0; cursor[i] = 0; }
}

__global__ void k_router(const float* __restrict__ glog, int* __restrict__ tidx,
    float* __restrict__ tw, int* __restrict__ counts) {
  int t = blockIdx.x * 256 + threadIdx.x;
  if (t >= TT) return;
  float l[EE];
#pragma unroll
  for (int e = 0; e < EE; e++) l[e] = glog[t * EE + e];
  int i0 = 0; float v0 = l[0];
#pragma unroll
  for (int e = 1; e < EE; e++) if (l[e] > v0) { v0 = l[e]; i0 = e; }
  int i1 = -1; float v1 = -1e30f;
#pragma unroll
  for (int e = 0; e < EE; e++) if (e != i0 && l[e] > v1) { v1 = l[e]; i1 = e; }
  float e1 = __expf(v1 - v0);
  float inv = 1.f / (1.f + e1);
  tw[t * 2] = inv; tw[t * 2 + 1] = e1 * inv;
  tidx[t * 2] = i0; tidx[t * 2 + 1] = i1;
  atomicAdd(&counts[i0], 1);
  atomicAdd(&counts[i1], 1);
}

__global__ void k_scan(const int* __restrict__ counts, int* __restrict__ bases,
                       int* __restrict__ cursor) {
  int b = 0;
  for (int e = 0; e < EE; e++) { bases[e] = b; cursor[e] = b; b += counts[e]; }
}

__global__ void k_assign(const int* __restrict__ tidx, int* __restrict__ cursor,
                         int* __restrict__ rows, int* __restrict__ gtok) {
  int t = blockIdx.x * 256 + threadIdx.x;
  if (t >= TT) return;
#pragma unroll
  for (int kk = 0; kk < 2; kk++) {
    int e = tidx[t * 2 + kk];
    int r = atomicAdd(&cursor[e], 1);
    rows[t * 2 + kk] = r;
    gtok[r] = t;
  }
}

// ---------------- expert FFN1: gh1 = gelu(gather(h) @ w1[e] + b1[e]) --------
__global__ __launch_bounds__(256) void k_expert1(const float* __restrict__ h,
    const float* __restrict__ w1, const float* __restrict__ b1,
    const int* __restrict__ gtok, const int* __restrict__ counts,
    const int* __restrict__ bases, float* __restrict__ gh1) {
  int e = blockIdx.z;
  int cnt = counts[e];
  int m0 = blockIdx.y * 128;
  if (m0 >= cnt) return;
  int base = bases[e];
  int n0 = blockIdx.x * 128;
  const float* W = w1 + (size_t)e * DD * FF;
  __shared__ float As[128][17];
  __shared__ float Bs[16][136];
  int tid = threadIdx.x;
  int tx = tid & 15, ty = tid >> 4;
  int ra = tid >> 1, ka0 = (tid & 1) * 8;
  int kb = tid >> 4, nb0 = (tid & 15) * 8;
  int tok = (m0 + ra < cnt) ? gtok[base + m0 + ra] : -1;
  const float* Arow = h + (size_t)(tok < 0 ? 0 : tok) * DD;
  float acc[8][8] = {};
  for (int k0 = 0; k0 < DD; k0 += 16) {
    float4 av0 = make_float4(0.f, 0.f, 0.f, 0.f), av1 = av0;
    if (tok >= 0) {
      av0 = *(const float4*)(Arow + k0 + ka0);
      av1 = *(const float4*)(Arow + k0 + ka0 + 4);
    }
    As[ra][ka0 + 0] = av0.x; As[ra][ka0 + 1] = av0.y;
    As[ra][ka0 + 2] = av0.z; As[ra][ka0 + 3] = av0.w;
    As[ra][ka0 + 4] = av1.x; As[ra][ka0 + 5] = av1.y;
    As[ra][ka0 + 6] = av1.z; As[ra][ka0 + 7] = av1.w;
    float4 bv0 = *(const float4*)(W + (size_t)(k0 + kb) * FF + n0 + nb0);
    float4 bv1 = *(const float4*)(W + (size_t)(k0 + kb) * FF + n0 + nb0 + 4);
    Bs[kb][nb0 + 0] = bv0.x; Bs[kb][nb0 + 1] = bv0.y;
    Bs[kb][nb0 + 2] = bv0.z; Bs[kb][nb0 + 3] = bv0.w;
    Bs[kb][nb0 + 4] = bv1.x; Bs[kb][nb0 + 5] = bv1.y;
    Bs[kb][nb0 + 6] = bv1.z; Bs[kb][nb0 + 7] = bv1.w;
    __syncthreads();
#pragma unroll
    for (int kk = 0; kk < 16; kk++) {
      float a[8], b[8];
#pragma unroll
      for (int i = 0; i < 8; i++) a[i] = As[ty * 8 + i][kk];
#pragma unroll
      for (int j = 0; j < 8; j++) b[j] = Bs[kk][tx * 8 + j];
#pragma unroll
      for (int i = 0; i < 8; i++) {
#pragma unroll
        for (int j = 0; j < 8; j++) acc[i][j] = fmaf(a[i], b[j], acc[i][j]);
      }
    }
    __syncthreads();
  }
#pragma unroll
  for (int i = 0; i < 8; i++) {
    int m = m0 + ty * 8 + i;
    if (m >= cnt) continue;
    float* orow = gh1 + (size_t)(base + m) * FF;
#pragma unroll
    for (int j = 0; j < 8; j++) {
      int n = n0 + tx * 8 + j;
      float vv = acc[i][j] + b1[e * FF + n];
      orow[n] = 0.5f * vv * (1.f + erff(vv * 0.70710678118654752f));
    }
  }
}

// ---------------- expert FFN2: go = gh1 @ w2[e] + b2[e] ----------------
__global__ __launch_bounds__(256) void k_expert2(const float* __restrict__ gh1,
    const float* __restrict__ w2, const float* __restrict__ b2,
    const int* __restrict__ counts, const int* __restrict__ bases,
    float* __restrict__ go) {
  int e = blockIdx.z;
  int cnt = counts[e];
  int m0 = blockIdx.y * 128;
  if (m0 >= cnt) return;
  int base = bases[e];
  int n0 = blockIdx.x * 128;
  const float* W = w2 + (size_t)e * FF * DD;
  __shared__ float As[128][17];
  __shared__ float Bs[16][136];
  int tid = threadIdx.x;
  int tx = tid & 15, ty = tid >> 4;
  int ra = tid >> 1, ka0 = (tid & 1) * 8;
  int kb = tid >> 4, nb0 = (tid & 15) * 8;
  bool arow_ok = (m0 + ra < cnt);
  const float* Arow = gh1 + (size_t)(base + (arow_ok ? m0 + ra : 0)) * FF;
  float acc[8][8] = {};
  for (int k0 = 0; k0 < FF; k0 += 16) {
    float4 av0 = make_float4(0.f, 0.f, 0.f, 0.f), av1 = av0;
    if (arow_ok) {
      av0 = *(const float4*)(Arow + k0 + ka0);
      av1 = *(const float4*)(Arow + k0 + ka0 + 4);
    }
    As[ra][ka0 + 0] = av0.x; As[ra][ka0 + 1] = av0.y;
    As[ra][ka0 + 2] = av0.z; As[ra][ka0 + 3] = av0.w;
    As[ra][ka0 + 4] = av1.x; As[ra][ka0 + 5] = av1.y;
    As[ra][ka0 + 6] = av1.z; As[ra][ka0 + 7] = av1.w;
    float4 bv0 = *(const float4*)(W + (size_t)(k0 + kb) * DD + n0 + nb0);
    float4 bv1 = *(const float4*)(W + (size_t)(k0 + kb) * DD + n0 + nb0 + 4);
    Bs[kb][nb0 + 0] = bv0.x; Bs[kb][nb0 + 1] = bv0.y;
    Bs[kb][nb0 + 2] = bv0.z; Bs[kb][nb0 + 3] = bv0.w;
    Bs[kb][nb0 + 4] = bv1.x; Bs[kb][nb0 + 5] = bv1.y;
    Bs[kb][nb0 + 6] = bv1.z; Bs[kb][nb0 + 7] = bv1.w;
    __syncthreads();
#pragma unroll
    for (int kk = 0; kk < 16; kk++) {
      float a[8], b[8];
#pragma unroll
      for (int i = 0; i < 8; i++) a[i] = As[ty * 8 + i][kk];
#pragma unroll
      for (int j = 0; j < 8; j++) b[j] = Bs[kk][tx * 8 + j];
#pragma unroll
      for (int i = 0; i < 8; i++) {
#pragma unroll
        for (int j = 0; j < 8; j++) acc[i][j] = fmaf(a[i], b[j], acc[i][j]);
      }
    }
    __syncthreads();
  }
#pragma unroll
  for (int i = 0; i < 8; i++) {
    int m = m0 + ty * 8 + i;
    if (m >= cnt) continue;
    float* orow = go + (size_t)(base + m) * DD;
#pragma unroll
    for (int j = 0; j < 8; j++) {
      int n = n0 + tx * 8 + j;
      orow[n] = acc[i][j] + b2[e * DD + n];
    }
  }
}

// ---------------- MoE scatter: x += w0*go[r0] + w1*go[r1] ----------------
__global__ __launch_bounds__(256) void k_scatter(const float* __restrict__ go,
    const int* __restrict__ rows, const float* __restrict__ tw, float* __restrict__ x) {
  int t = blockIdx.x;
  int r0 = rows[t * 2], r1 = rows[t * 2 + 1];
  float w0 = tw[t * 2], w1 = tw[t * 2 + 1];
  float* xr = x + (size_t)t * DD;
  const float* g0 = go + (size_t)r0 * DD;
  const float* g1 = go + (size_t)r1 * DD;
  for (int d = threadIdx.x; d < DD; d += 256)
    xr[d] += w0 * g0[d] + w1 * g1[d];
}

// ---------------- lm_head: out = hf @ emb^T ----------------
__global__ __launch_bounds__(256) void k_lmhead(const float* __restrict__ A,
    const float* __restrict__ Bt, float* __restrict__ C) {
  __shared__ float As[128][17];
  __shared__ float Bs[16][136];
  int tid = threadIdx.x;
  int tx = tid & 15, ty = tid >> 4;
  int n0 = blockIdx.x * 128, m0 = blockIdx.y * 128;
  int ra = tid >> 1, ka0 = (tid & 1) * 8;
  float acc[8][8] = {};
  for (int k0 = 0; k0 < DD; k0 += 16) {
    const float* Arow = A + (size_t)(m0 + ra) * DD;
    float4 av0 = *(const float4*)(Arow + k0 + ka0);
    float4 av1 = *(const float4*)(Arow + k0 + ka0 + 4);
    As[ra][ka0 + 0] = av0.x; As[ra][ka0 + 1] = av0.y;
    As[ra][ka0 + 2] = av0.z; As[ra][ka0 + 3] = av0.w;
    As[ra][ka0 + 4] = av1.x; As[ra][ka0 + 5] = av1.y;
    As[ra][ka0 + 6] = av1.z; As[ra][ka0 + 7] = av1.w;
    const float* Brow = Bt + (size_t)(n0 + ra) * DD;
    float4 bv0 = *(const float4*)(Brow + k0 + ka0);
    float4 bv1 = *(const float4*)(Brow + k0 + ka0 + 4);
    Bs[ka0 + 0][ra] = bv0.x; Bs[ka0 + 1][ra] = bv0.y;
    Bs[ka0 + 2][ra] = bv0.z; Bs[ka0 + 3][ra] = bv0.w;
    Bs[ka0 + 4][ra] = bv1.x; Bs[ka0 + 5][ra] = bv1.y;
    Bs[ka0 + 6][ra] = bv1.z; Bs[ka0 + 7][ra] = bv1.w;
    __syncthreads();
#pragma unroll
    for (int kk = 0; kk < 16; kk++) {
      float a[8], b[8];
#pragma unroll
      for (int i = 0; i < 8; i++) a[i] = As[ty * 8 + i][kk];
#pragma unroll
      for (int j = 0; j < 8; j++) b[j] = Bs[kk][tx * 8 + j];
#pragma unroll
      for (int i = 0; i < 8; i++) {
#pragma unroll
        for (int j = 0; j < 8; j++) acc[i][j] = fmaf(a[i], b[j], acc[i][j]);
      }
    }
    __syncthreads();
  }
#pragma unroll
  for (int i = 0; i < 8; i++) {
    int m = m0 + ty * 8 + i;
    float* crow = C + (size_t)m * VV;
    float4 p0 = make_float4(acc[i][0], acc[i][1], acc[i][2], acc[i][3]);
    float4 p1 = make_float4(acc[i][4], acc[i][5], acc[i][6], acc[i][7]);
    *(float4*)(crow + n0 + tx * 8) = p0;
    *(float4*)(crow + n0 + tx * 8 + 4) = p1;
  }
}

// ================= host =================
extern "C" void kernel_launch(void* const* d_in, const int* in_sizes, int n_in,
                              void* d_out, int out_size, void* d_ws, size_t ws_size,
                              hipStream_t stream) {
  (void)in_sizes; (void)n_in; (void)out_size; (void)ws_size;
  const int* tok   = (const int*)d_in[0];
  const float* emb = (const float*)d_in[1];
  const float* pos = (const float*)d_in[2];
  const float* wq  = (const float*)d_in[3];
  const float* bq  = (const float*)d_in[4];
  const float* wk  = (const float*)d_in[5];
  const float* bk  = (const float*)d_in[6];
  const float* wv  = (const float*)d_in[7];
  const float* bvv = (const float*)d_in[8];
  const float* wo  = (const float*)d_in[9];
  const float* bo  = (const float*)d_in[10];
  const float* ln1 = (const float*)d_in[11];
  const float* ln2 = (const float*)d_in[12];
  const float* gw  = (const float*)d_in[13];
  const float* gb  = (const float*)d_in[14];
  const float* w1  = (const float*)d_in[15];
  const float* b1  = (const float*)d_in[16];
  const float* w2  = (const float*)d_in[17];
  const float* b2  = (const float*)d_in[18];
  const float* lnf = (const float*)d_in[19];

  // scratch carved from d_out (65.5M f32; all dead before lm_head writes)
  float* ob  = (float*)d_out;
  float* qb  = ob;                              // 1.57M
  float* kb  = qb + (size_t)TT * DD;
  float* vb  = kb + (size_t)TT * DD;
  float* ao  = vb + (size_t)TT * DD;
  float* gh1 = ao + (size_t)TT * DD;            // 12.58M
  float* go  = gh1 + (size_t)TT * 2 * FF;       // 3.15M
  float* x   = go + (size_t)TT * 2 * DD;        // 1.57M
  float* h   = x + (size_t)TT * DD;             // 1.57M
  float* glog= h + (size_t)TT * DD;
  float* tw  = glog + (size_t)TT * EE;
  int* tidx  = (int*)(tw + (size_t)TT * 2);
  int* rows  = tidx + TT * 2;
  int* gtok  = rows + TT * 2;
  int* counts= gtok + TT * 2;
  int* cursor= counts + EE;
  int* bases = cursor + EE;
  // total ~25.3M floats < 65.5M

  // final rmsnorm output must survive lm_head's d_out writes -> d_ws (6.3 MB)
  float* hf = (float*)d_ws;

  k_embed<<<TT, 256, 0, stream>>>(tok, emb, pos, x);

  for (int l = 0; l < NLAYER; l++) {
    const float* wq_l = wq + (size_t)l * DD * DD;
    const float* wk_l = wk + (size_t)l * DD * DD;
    const float* wv_l = wv + (size_t)l * DD * DD;
    const float* wo_l = wo + (size_t)l * DD * DD;
    const float* bq_l = bq + (size_t)l * DD;
    const float* bk_l = bk + (size_t)l * DD;
    const float* bv_l = bvv + (size_t)l * DD;
    const float* bo_l = bo + (size_t)l * DD;

    k_rmsnorm<<<TT, 256, 0, stream>>>(x, ln1 + (size_t)l * DD, h);
    dim3 gp(DD / 64, TT / 64);
    k_gemm_nn<true, false><<<gp, 256, 0, stream>>>(h, wq_l, bq_l, qb, TT, DD, DD);
    k_gemm_nn<true, false><<<gp, 256, 0, stream>>>(h, wk_l, bk_l, kb, TT, DD, DD);
    k_gemm_nn<true, false><<<gp, 256, 0, stream>>>(h, wv_l, bv_l, vb, TT, DD, DD);
    k_attn<<<dim3(SS / QBLK, HH, BB), 256, 0, stream>>>(qb, kb, vb, ao);
    k_gemm_nn<true, true><<<gp, 256, 0, stream>>>(ao, wo_l, bo_l, x, TT, DD, DD);

    k_rmsnorm<<<TT, 256, 0, stream>>>(x, ln2 + (size_t)l * DD, h);
    k_gate<<<TT, 256, 0, stream>>>(h, gw + (size_t)l * DD * EE, gb + (size_t)l * EE, glog);
    k_zero<<<1, 64, 0, stream>>>(counts, cursor);
    k_router<<<TT / 256, 256, 0, stream>>>(glog, tidx, tw, counts);
    k_scan<<<1, 1, 0, stream>>>(counts, bases, cursor);
    k_assign<<<TT / 256, 256, 0, stream>>>(tidx, cursor, rows, gtok);
    k_expert1<<<dim3(FF / 128, TT / 128, EE), 256, 0, stream>>>(
        h, w1 + (size_t)l * EE * DD * FF, b1 + (size_t)l * EE * FF,
        gtok, counts, bases, gh1);
    k_expert2<<<dim3(DD / 128, TT / 128, EE), 256, 0, stream>>>(
        gh1, w2 + (size_t)l * EE * FF * DD, b2 + (size_t)l * EE * DD,
        counts, bases, go);
    k_scatter<<<TT, 256, 0, stream>>>(go, rows, tw, x);
  }

  k_rmsnorm<<<TT, 256, 0, stream>>>(x, lnf, hf);
  k_lmhead<<<dim3(VV / 128, TT / 128), 256, 0, stream>>>(hf, emb, (float*)d_out);
}

// Round 4
// 2771.541 us; speedup vs baseline: 1.5688x; 1.5688x over previous
//
#include <hip/hip_runtime.h>
#include <math.h>

#define TT 2048      // B*S tokens
#define BB 2
#define SS 1024
#define DD 768
#define HH 12
#define FF 3072
#define EE 8
#define VV 32000
#define NLAYER 2
#define QBLK 8

typedef __attribute__((ext_vector_type(8))) short bf16x8;
typedef __attribute__((ext_vector_type(4))) float f32x4;

static __device__ __forceinline__ unsigned short f2b(float f) {
  unsigned u = __float_as_uint(f);
  unsigned r = (u + 0x7fffu + ((u >> 16) & 1u)) >> 16;
  return (unsigned short)r;
}
static __device__ __forceinline__ unsigned int pk2(float a, float b) {
  return (unsigned int)f2b(a) | ((unsigned int)f2b(b) << 16);
}

// ---------------- embedding: x = emb[tok] + pos ----------------
__global__ __launch_bounds__(256) void k_embed(const int* __restrict__ tok,
    const float* __restrict__ emb, const float* __restrict__ pos,
    float* __restrict__ x) {
  int t = blockIdx.x;
  int s = t & (SS - 1);
  int tk = tok[t];
  const float* er = emb + (size_t)tk * DD;
  const float* pr = pos + (size_t)s * DD;
  float* xr = x + (size_t)t * DD;
  for (int d = threadIdx.x; d < DD; d += 256)
    xr[d] = er[d] + pr[d];
}

// ------------- rmsnorm: writes f32 out AND bf16 out -------------
__global__ __launch_bounds__(256) void k_rmsnorm(const float* __restrict__ x,
    const float* __restrict__ w, float* __restrict__ out,
    unsigned short* __restrict__ outb) {
  int t = blockIdx.x;
  const float* xr = x + (size_t)t * DD;
  int tid = threadIdx.x;
  float v0 = xr[tid], v1 = xr[tid + 256], v2 = xr[tid + 512];
  float ss = v0 * v0 + v1 * v1 + v2 * v2;
  for (int off = 32; off > 0; off >>= 1) ss += __shfl_down(ss, off, 64);
  __shared__ float ps[4];
  int wid = tid >> 6, lane = tid & 63;
  if (lane == 0) ps[wid] = ss;
  __syncthreads();
  float r = rsqrtf((ps[0] + ps[1] + ps[2] + ps[3]) * (1.0f / DD) + 1e-6f);
  float* orow = out + (size_t)t * DD;
  unsigned short* brow = outb + (size_t)t * DD;
  float o0 = v0 * r * w[tid], o1 = v1 * r * w[tid + 256], o2 = v2 * r * w[tid + 512];
  orow[tid] = o0; orow[tid + 256] = o1; orow[tid + 512] = o2;
  brow[tid] = f2b(o0); brow[tid + 256] = f2b(o1); brow[tid + 512] = f2b(o2);
}

// ------------- transpose+convert: f32 [R][C] -> bf16 [C][R] -------------
__global__ __launch_bounds__(256) void k_tcvt(const float* __restrict__ src,
    unsigned short* __restrict__ dst, int R, int C, size_t srcZ, size_t dstZ) {
  src += (size_t)blockIdx.z * srcZ;
  dst += (size_t)blockIdx.z * dstZ;
  __shared__ unsigned short tile[32][40];
  int t = threadIdx.x;
  int r = t >> 3, c4 = (t & 7) * 4;
  int r0 = blockIdx.y * 32, c0 = blockIdx.x * 32;
  float4 v = *(const float4*)(src + (size_t)(r0 + r) * C + c0 + c4);
  tile[r][c4 + 0] = f2b(v.x); tile[r][c4 + 1] = f2b(v.y);
  tile[r][c4 + 2] = f2b(v.z); tile[r][c4 + 3] = f2b(v.w);
  __syncthreads();
  int cc = t >> 3, r4 = (t & 7) * 4;
  ushort4 o;
  o.x = tile[r4 + 0][cc]; o.y = tile[r4 + 1][cc];
  o.z = tile[r4 + 2][cc]; o.w = tile[r4 + 3][cc];
  *(ushort4*)(dst + (size_t)(c0 + cc) * R + r0 + r4) = o;
}

// ======== f32 128x128-tile projection GEMM (router-feeding path) ========
// Up to 3 column-thirds select W/bias/C; ADD accumulates into C (residual).
template<bool ADD>
__global__ __launch_bounds__(256) void k_proj(const float* __restrict__ A,
    const float* __restrict__ W0, const float* __restrict__ W1, const float* __restrict__ W2,
    const float* __restrict__ b0, const float* __restrict__ b1, const float* __restrict__ b2,
    float* __restrict__ C0, float* __restrict__ C1, float* __restrict__ C2,
    int K, int Nthird) {
  int n0g = blockIdx.x * 128;
  int sel = n0g / Nthird;
  int n0 = n0g - sel * Nthird;
  const float* W = sel == 0 ? W0 : sel == 1 ? W1 : W2;
  const float* bias = sel == 0 ? b0 : sel == 1 ? b1 : b2;
  float* C = sel == 0 ? C0 : sel == 1 ? C1 : C2;
  int m0 = blockIdx.y * 128;
  __shared__ float As[128][17];
  __shared__ float Bs[16][136];
  int tid = threadIdx.x;
  int tx = tid & 15, ty = tid >> 4;
  int ra = tid >> 1, ka0 = (tid & 1) * 8;
  int kb = tid >> 4, nb0 = (tid & 15) * 8;
  const float* Arow = A + (size_t)(m0 + ra) * K;
  float acc[8][8] = {};
  for (int k0 = 0; k0 < K; k0 += 16) {
    float4 av0 = *(const float4*)(Arow + k0 + ka0);
    float4 av1 = *(const float4*)(Arow + k0 + ka0 + 4);
    As[ra][ka0 + 0] = av0.x; As[ra][ka0 + 1] = av0.y;
    As[ra][ka0 + 2] = av0.z; As[ra][ka0 + 3] = av0.w;
    As[ra][ka0 + 4] = av1.x; As[ra][ka0 + 5] = av1.y;
    As[ra][ka0 + 6] = av1.z; As[ra][ka0 + 7] = av1.w;
    float4 bv0 = *(const float4*)(W + (size_t)(k0 + kb) * Nthird + n0 + nb0);
    float4 bv1 = *(const float4*)(W + (size_t)(k0 + kb) * Nthird + n0 + nb0 + 4);
    Bs[kb][nb0 + 0] = bv0.x; Bs[kb][nb0 + 1] = bv0.y;
    Bs[kb][nb0 + 2] = bv0.z; Bs[kb][nb0 + 3] = bv0.w;
    Bs[kb][nb0 + 4] = bv1.x; Bs[kb][nb0 + 5] = bv1.y;
    Bs[kb][nb0 + 6] = bv1.z; Bs[kb][nb0 + 7] = bv1.w;
    __syncthreads();
#pragma unroll
    for (int kk = 0; kk < 16; kk++) {
      float a[8], b[8];
#pragma unroll
      for (int i = 0; i < 8; i++) a[i] = As[ty * 8 + i][kk];
#pragma unroll
      for (int j = 0; j < 8; j++) b[j] = Bs[kk][tx * 8 + j];
#pragma unroll
      for (int i = 0; i < 8; i++) {
#pragma unroll
        for (int j = 0; j < 8; j++) acc[i][j] = fmaf(a[i], b[j], acc[i][j]);
      }
    }
    __syncthreads();
  }
#pragma unroll
  for (int i = 0; i < 8; i++) {
    int m = m0 + ty * 8 + i;
    float* crow = C + (size_t)m * Nthird;
#pragma unroll
    for (int j = 0; j < 8; j++) {
      int n = n0 + tx * 8 + j;
      float v = acc[i][j] + bias[n];
      if (ADD) crow[n] += v; else crow[n] = v;
    }
  }
}

// ---------------- attention (f32, separate q/k/v) ----------------
__global__ __launch_bounds__(256) void k_attn(const float* __restrict__ q,
    const float* __restrict__ k, const float* __restrict__ v, float* __restrict__ ao) {
  int b = blockIdx.z, hh = blockIdx.y, q0 = blockIdx.x * QBLK;
  __shared__ float qs[QBLK][64];
  __shared__ float sc[QBLK][SS];
  __shared__ float red[QBLK][8];
  int tid = threadIdx.x;
  const size_t hoff = (size_t)b * SS * DD + (size_t)hh * 64;
  for (int i = tid; i < QBLK * 64; i += 256) {
    int qi = i >> 6, d = i & 63;
    qs[qi][d] = q[hoff + (size_t)(q0 + qi) * DD + d];
  }
  __syncthreads();
  int kmax = q0 + QBLK;
  for (int j = tid; j < kmax; j += 256) {
    const float* kr = k + hoff + (size_t)j * DD;
    float p[QBLK];
#pragma unroll
    for (int qi = 0; qi < QBLK; qi++) p[qi] = 0.f;
#pragma unroll 4
    for (int c = 0; c < 16; c++) {
      float4 kv = *(const float4*)(kr + c * 4);
#pragma unroll
      for (int qi = 0; qi < QBLK; qi++)
        p[qi] += qs[qi][c * 4] * kv.x + qs[qi][c * 4 + 1] * kv.y +
                 qs[qi][c * 4 + 2] * kv.z + qs[qi][c * 4 + 3] * kv.w;
    }
#pragma unroll
    for (int qi = 0; qi < QBLK; qi++)
      sc[qi][j] = (j <= q0 + qi) ? p[qi] * 0.125f : -1e30f;
  }
  __syncthreads();
  int wid = tid >> 6, lane = tid & 63;
#pragma unroll
  for (int qi = 0; qi < QBLK; qi++) {
    float mx = -1e30f;
    for (int j = tid; j < kmax; j += 256) mx = fmaxf(mx, sc[qi][j]);
    for (int off = 32; off > 0; off >>= 1) mx = fmaxf(mx, __shfl_down(mx, off, 64));
    if (lane == 0) red[qi][wid] = mx;
  }
  __syncthreads();
#pragma unroll
  for (int qi = 0; qi < QBLK; qi++) {
    float mx = fmaxf(fmaxf(red[qi][0], red[qi][1]), fmaxf(red[qi][2], red[qi][3]));
    float s = 0.f;
    for (int j = tid; j < kmax; j += 256) {
      float e = __expf(sc[qi][j] - mx);
      sc[qi][j] = e;
      s += e;
    }
    for (int off = 32; off > 0; off >>= 1) s += __shfl_down(s, off, 64);
    if (lane == 0) red[qi][4 + wid] = s;
  }
  __syncthreads();
  int d = tid & 63, g = tid >> 6;
  for (int qi = g; qi < QBLK; qi += 4) {
    float inv = 1.f / (red[qi][4] + red[qi][5] + red[qi][6] + red[qi][7]);
    float acc = 0.f;
    int jend = q0 + qi + 1;
    const float* vp = v + hoff + d;
    for (int j = 0; j < jend; j++) acc = fmaf(sc[qi][j], vp[(size_t)j * DD], acc);
    ao[hoff + (size_t)(q0 + qi) * DD + d] = acc * inv;
  }
}

// ---------------- gate logits ----------------
__global__ __launch_bounds__(256) void k_gate(const float* __restrict__ h,
    const float* __restrict__ gw, const float* __restrict__ gb,
    float* __restrict__ glog) {
  __shared__ float hr[DD];
  int t = blockIdx.x;
  for (int d = threadIdx.x; d < DD; d += 256) hr[d] = h[(size_t)t * DD + d];
  __syncthreads();
  int e = threadIdx.x >> 5, j = threadIdx.x & 31;
  float s = 0.f;
  for (int d = j; d < DD; d += 32) s += hr[d] * gw[d * EE + e];
  for (int off = 16; off > 0; off >>= 1) s += __shfl_down(s, off, 32);
  if (j == 0) glog[t * EE + e] = s + gb[e];
}

// ---------------- router ----------------
__global__ void k_zero(int* counts, int* cursor) {
  int i = threadIdx.x;
  if (i < EE) { counts[i] = 0; cursor[i] = 0; }
}

__global__ void k_router(const float* __restrict__ glog, int* __restrict__ tidx,
    float* __restrict__ tw, int* __restrict__ counts) {
  int t = blockIdx.x * 256 + threadIdx.x;
  if (t >= TT) return;
  float l[EE];
#pragma unroll
  for (int e = 0; e < EE; e++) l[e] = glog[t * EE + e];
  int i0 = 0; float v0 = l[0];
#pragma unroll
  for (int e = 1; e < EE; e++) if (l[e] > v0) { v0 = l[e]; i0 = e; }
  int i1 = -1; float v1 = -1e30f;
#pragma unroll
  for (int e = 0; e < EE; e++) if (e != i0 && l[e] > v1) { v1 = l[e]; i1 = e; }
  float e1 = __expf(v1 - v0);
  float inv = 1.f / (1.f + e1);
  tw[t * 2] = inv; tw[t * 2 + 1] = e1 * inv;
  tidx[t * 2] = i0; tidx[t * 2 + 1] = i1;
  atomicAdd(&counts[i0], 1);
  atomicAdd(&counts[i1], 1);
}

__global__ void k_scan(const int* __restrict__ counts, int* __restrict__ bases,
                       int* __restrict__ cursor) {
  int b = 0;
  for (int e = 0; e < EE; e++) { bases[e] = b; cursor[e] = b; b += counts[e]; }
}

__global__ void k_assign(const int* __restrict__ tidx, int* __restrict__ cursor,
                         int* __restrict__ rows, int* __restrict__ gtok) {
  int t = blockIdx.x * 256 + threadIdx.x;
  if (t >= TT) return;
#pragma unroll
  for (int kk = 0; kk < 2; kk++) {
    int e = tidx[t * 2 + kk];
    int r = atomicAdd(&cursor[e], 1);
    rows[t * 2 + kk] = r;
    gtok[r] = t;
  }
}

// ---------------- f32 expert FFN1 (layer feeding a router) ----------------
__global__ __launch_bounds__(256) void k_expert1(const float* __restrict__ h,
    const float* __restrict__ w1, const float* __restrict__ b1,
    const int* __restrict__ gtok, const int* __restrict__ counts,
    const int* __restrict__ bases, float* __restrict__ gh1) {
  int e = blockIdx.z;
  int cnt = counts[e];
  int m0 = blockIdx.y * 128;
  if (m0 >= cnt) return;
  int base = bases[e];
  int n0 = blockIdx.x * 128;
  const float* W = w1 + (size_t)e * DD * FF;
  __shared__ float As[128][17];
  __shared__ float Bs[16][136];
  int tid = threadIdx.x;
  int tx = tid & 15, ty = tid >> 4;
  int ra = tid >> 1, ka0 = (tid & 1) * 8;
  int kb = tid >> 4, nb0 = (tid & 15) * 8;
  int tok = (m0 + ra < cnt) ? gtok[base + m0 + ra] : -1;
  const float* Arow = h + (size_t)(tok < 0 ? 0 : tok) * DD;
  float acc[8][8] = {};
  for (int k0 = 0; k0 < DD; k0 += 16) {
    float4 av0 = make_float4(0.f, 0.f, 0.f, 0.f), av1 = av0;
    if (tok >= 0) {
      av0 = *(const float4*)(Arow + k0 + ka0);
      av1 = *(const float4*)(Arow + k0 + ka0 + 4);
    }
    As[ra][ka0 + 0] = av0.x; As[ra][ka0 + 1] = av0.y;
    As[ra][ka0 + 2] = av0.z; As[ra][ka0 + 3] = av0.w;
    As[ra][ka0 + 4] = av1.x; As[ra][ka0 + 5] = av1.y;
    As[ra][ka0 + 6] = av1.z; As[ra][ka0 + 7] = av1.w;
    float4 bv0 = *(const float4*)(W + (size_t)(k0 + kb) * FF + n0 + nb0);
    float4 bv1 = *(const float4*)(W + (size_t)(k0 + kb) * FF + n0 + nb0 + 4);
    Bs[kb][nb0 + 0] = bv0.x; Bs[kb][nb0 + 1] = bv0.y;
    Bs[kb][nb0 + 2] = bv0.z; Bs[kb][nb0 + 3] = bv0.w;
    Bs[kb][nb0 + 4] = bv1.x; Bs[kb][nb0 + 5] = bv1.y;
    Bs[kb][nb0 + 6] = bv1.z; Bs[kb][nb0 + 7] = bv1.w;
    __syncthreads();
#pragma unroll
    for (int kk = 0; kk < 16; kk++) {
      float a[8], b[8];
#pragma unroll
      for (int i = 0; i < 8; i++) a[i] = As[ty * 8 + i][kk];
#pragma unroll
      for (int j = 0; j < 8; j++) b[j] = Bs[kk][tx * 8 + j];
#pragma unroll
      for (int i = 0; i < 8; i++) {
#pragma unroll
        for (int j = 0; j < 8; j++) acc[i][j] = fmaf(a[i], b[j], acc[i][j]);
      }
    }
    __syncthreads();
  }
#pragma unroll
  for (int i = 0; i < 8; i++) {
    int m = m0 + ty * 8 + i;
    if (m >= cnt) continue;
    float* orow = gh1 + (size_t)(base + m) * FF;
#pragma unroll
    for (int j = 0; j < 8; j++) {
      int n = n0 + tx * 8 + j;
      float vv = acc[i][j] + b1[e * FF + n];
      orow[n] = 0.5f * vv * (1.f + erff(vv * 0.70710678118654752f));
    }
  }
}

// ---------------- f32 expert FFN2 ----------------
__global__ __launch_bounds__(256) void k_expert2(const float* __restrict__ gh1,
    const float* __restrict__ w2, const float* __restrict__ b2,
    const int* __restrict__ counts, const int* __restrict__ bases,
    float* __restrict__ go) {
  int e = blockIdx.z;
  int cnt = counts[e];
  int m0 = blockIdx.y * 128;
  if (m0 >= cnt) return;
  int base = bases[e];
  int n0 = blockIdx.x * 128;
  const float* W = w2 + (size_t)e * FF * DD;
  __shared__ float As[128][17];
  __shared__ float Bs[16][136];
  int tid = threadIdx.x;
  int tx = tid & 15, ty = tid >> 4;
  int ra = tid >> 1, ka0 = (tid & 1) * 8;
  int kb = tid >> 4, nb0 = (tid & 15) * 8;
  bool arow_ok = (m0 + ra < cnt);
  const float* Arow = gh1 + (size_t)(base + (arow_ok ? m0 + ra : 0)) * FF;
  float acc[8][8] = {};
  for (int k0 = 0; k0 < FF; k0 += 16) {
    float4 av0 = make_float4(0.f, 0.f, 0.f, 0.f), av1 = av0;
    if (arow_ok) {
      av0 = *(const float4*)(Arow + k0 + ka0);
      av1 = *(const float4*)(Arow + k0 + ka0 + 4);
    }
    As[ra][ka0 + 0] = av0.x; As[ra][ka0 + 1] = av0.y;
    As[ra][ka0 + 2] = av0.z; As[ra][ka0 + 3] = av0.w;
    As[ra][ka0 + 4] = av1.x; As[ra][ka0 + 5] = av1.y;
    As[ra][ka0 + 6] = av1.z; As[ra][ka0 + 7] = av1.w;
    float4 bv0 = *(const float4*)(W + (size_t)(k0 + kb) * DD + n0 + nb0);
    float4 bv1 = *(const float4*)(W + (size_t)(k0 + kb) * DD + n0 + nb0 + 4);
    Bs[kb][nb0 + 0] = bv0.x; Bs[kb][nb0 + 1] = bv0.y;
    Bs[kb][nb0 + 2] = bv0.z; Bs[kb][nb0 + 3] = bv0.w;
    Bs[kb][nb0 + 4] = bv1.x; Bs[kb][nb0 + 5] = bv1.y;
    Bs[kb][nb0 + 6] = bv1.z; Bs[kb][nb0 + 7] = bv1.w;
    __syncthreads();
#pragma unroll
    for (int kk = 0; kk < 16; kk++) {
      float a[8], b[8];
#pragma unroll
      for (int i = 0; i < 8; i++) a[i] = As[ty * 8 + i][kk];
#pragma unroll
      for (int j = 0; j < 8; j++) b[j] = Bs[kk][tx * 8 + j];
#pragma unroll
      for (int i = 0; i < 8; i++) {
#pragma unroll
        for (int j = 0; j < 8; j++) acc[i][j] = fmaf(a[i], b[j], acc[i][j]);
      }
    }
    __syncthreads();
  }
#pragma unroll
  for (int i = 0; i < 8; i++) {
    int m = m0 + ty * 8 + i;
    if (m >= cnt) continue;
    float* orow = go + (size_t)(base + m) * DD;
#pragma unroll
    for (int j = 0; j < 8; j++) {
      int n = n0 + tx * 8 + j;
      orow[n] = acc[i][j] + b2[e * DD + n];
    }
  }
}

// =============== bf16 MFMA GEMM (routing-irrelevant work only) ===============
// EPI: 0 = store f32 (+bias), 2 = gelu -> bf16 (+bias). BF32: stage B from f32.
template<bool EXPERT, bool GATHER, bool BIAS, int EPI, bool BF32>
__global__ __launch_bounds__(256) void k_mfma(
    const unsigned short* __restrict__ A, const void* __restrict__ Bt,
    const float* __restrict__ bias, void* __restrict__ Cv,
    int M, int N, int K,
    const int* __restrict__ gtok, const int* __restrict__ counts,
    const int* __restrict__ bases) {
  int cnt = M, base = 0;
  if (EXPERT) {
    int e = blockIdx.z;
    cnt = counts[e]; base = bases[e];
    if (BIAS) bias += (size_t)e * N;
  }
  int m0 = blockIdx.y * 128;
  if (EXPERT && m0 >= cnt) return;
  int n0 = blockIdx.x * 128;

  __shared__ unsigned short As[128 * 40];
  __shared__ unsigned short Bs[128 * 40];

  int tid = threadIdx.x;
  int srow = tid >> 1;            // 0..127
  int scol = (tid & 1) * 16;      // 0 or 16 (elements)

  bool avalid = true;
  const unsigned short* arow;
  if (GATHER) {
    avalid = (m0 + srow) < cnt;
    int tk = avalid ? gtok[base + m0 + srow] : 0;
    arow = A + (size_t)tk * K + scol;
  } else if (EXPERT) {
    avalid = (m0 + srow) < cnt;
    arow = A + (size_t)(base + m0 + (avalid ? srow : 0)) * K + scol;
  } else {
    arow = A + (size_t)(m0 + srow) * K + scol;
  }

  const unsigned short* brow16 = nullptr;
  const float* browf = nullptr;
  if (BF32) {
    browf = (const float*)Bt + (size_t)(n0 + srow) * K + scol;
  } else {
    const unsigned short* B16 = (const unsigned short*)Bt;
    if (EXPERT) B16 += (size_t)blockIdx.z * N * K;
    brow16 = B16 + (size_t)(n0 + srow) * K + scol;
  }

  unsigned short* As_w = As + srow * 40 + scol;
  unsigned short* Bs_w = Bs + srow * 40 + scol;

  int lane = tid & 63, wid = tid >> 6;
  int wr = wid >> 1, wc = wid & 1;
  int l15 = lane & 15, lg = lane >> 4;
  const unsigned short* Ar = As + ((wr * 64 + l15) * 40 + lg * 8);
  const unsigned short* Br = Bs + ((wc * 64 + l15) * 40 + lg * 8);

  f32x4 acc[4][4];
#pragma unroll
  for (int i = 0; i < 4; i++)
#pragma unroll
    for (int j = 0; j < 4; j++) acc[i][j] = (f32x4){0.f, 0.f, 0.f, 0.f};

  for (int k0 = 0; k0 < K; k0 += 32) {
    uint4 av0 = {0, 0, 0, 0}, av1 = {0, 0, 0, 0};
    if (avalid) {
      av0 = *(const uint4*)(arow + k0);
      av1 = *(const uint4*)(arow + k0 + 8);
    }
    uint4 bv0, bv1;
    if (BF32) {
      float4 f0 = *(const float4*)(browf + k0);
      float4 f1 = *(const float4*)(browf + k0 + 4);
      float4 f2 = *(const float4*)(browf + k0 + 8);
      float4 f3 = *(const float4*)(browf + k0 + 12);
      bv0 = make_uint4(pk2(f0.x, f0.y), pk2(f0.z, f0.w), pk2(f1.x, f1.y), pk2(f1.z, f1.w));
      bv1 = make_uint4(pk2(f2.x, f2.y), pk2(f2.z, f2.w), pk2(f3.x, f3.y), pk2(f3.z, f3.w));
    } else {
      bv0 = *(const uint4*)(brow16 + k0);
      bv1 = *(const uint4*)(brow16 + k0 + 8);
    }
    *(uint4*)As_w = av0; *(uint4*)(As_w + 8) = av1;
    *(uint4*)Bs_w = bv0; *(uint4*)(Bs_w + 8) = bv1;
    __syncthreads();
    bf16x8 af[4], bfr[4];
#pragma unroll
    for (int f = 0; f < 4; f++) {
      af[f]  = *(const bf16x8*)(Ar + f * 640);
      bfr[f] = *(const bf16x8*)(Br + f * 640);
    }
#pragma unroll
    for (int i = 0; i < 4; i++)
#pragma unroll
      for (int j = 0; j < 4; j++)
        acc[i][j] = __builtin_amdgcn_mfma_f32_16x16x32_bf16(af[i], bfr[j], acc[i][j], 0, 0, 0);
    __syncthreads();
  }

#pragma unroll
  for (int j = 0; j < 4; j++) {
    int n = n0 + wc * 64 + j * 16 + l15;
    float bb = BIAS ? bias[n] : 0.f;
#pragma unroll
    for (int i = 0; i < 4; i++) {
      int mb = m0 + wr * 64 + i * 16 + lg * 4;
#pragma unroll
      for (int r = 0; r < 4; r++) {
        int m = mb + r;
        if (EXPERT && m >= cnt) continue;
        size_t off = (size_t)(base + m) * N + n;
        float v = acc[i][j][r] + bb;
        if (EPI == 0) {
          ((float*)Cv)[off] = v;
        } else {
          float g = 0.5f * v * (1.f + erff(v * 0.70710678118654752f));
          ((unsigned short*)Cv)[off] = f2b(g);
        }
      }
    }
  }
}

// ---------------- MoE scatter: x += w0*go[r0] + w1*go[r1] ----------------
__global__ __launch_bounds__(256) void k_scatter(const float* __restrict__ go,
    const int* __restrict__ rows, const float* __restrict__ tw, float* __restrict__ x) {
  int t = blockIdx.x;
  int r0 = rows[t * 2], r1 = rows[t * 2 + 1];
  float w0 = tw[t * 2], w1 = tw[t * 2 + 1];
  float* xr = x + (size_t)t * DD;
  const float* g0 = go + (size_t)r0 * DD;
  const float* g1 = go + (size_t)r1 * DD;
  for (int d = threadIdx.x; d < DD; d += 256)
    xr[d] += w0 * g0[d] + w1 * g1[d];
}

// ================= host =================
extern "C" void kernel_launch(void* const* d_in, const int* in_sizes, int n_in,
                              void* d_out, int out_size, void* d_ws, size_t ws_size,
                              hipStream_t stream) {
  (void)in_sizes; (void)n_in; (void)out_size; (void)ws_size;
  const int* tok   = (const int*)d_in[0];
  const float* emb = (const float*)d_in[1];
  const float* pos = (const float*)d_in[2];
  const float* wq  = (const float*)d_in[3];
  const float* bq  = (const float*)d_in[4];
  const float* wk  = (const float*)d_in[5];
  const float* bk  = (const float*)d_in[6];
  const float* wv  = (const float*)d_in[7];
  const float* bvv = (const float*)d_in[8];
  const float* wo  = (const float*)d_in[9];
  const float* bo  = (const float*)d_in[10];
  const float* ln1 = (const float*)d_in[11];
  const float* ln2 = (const float*)d_in[12];
  const float* gw  = (const float*)d_in[13];
  const float* gb  = (const float*)d_in[14];
  const float* w1  = (const float*)d_in[15];
  const float* b1  = (const float*)d_in[16];
  const float* w2  = (const float*)d_in[17];
  const float* b2  = (const float*)d_in[18];
  const float* lnf = (const float*)d_in[19];

  // ---- scratch carved from d_out (65.5M f32; all dead before lm_head) ----
  float* fp = (float*)d_out;
  float* qb   = fp; fp += (size_t)TT * DD;
  float* kb   = fp; fp += (size_t)TT * DD;
  float* vb   = fp; fp += (size_t)TT * DD;
  float* ao   = fp; fp += (size_t)TT * DD;
  float* x    = fp; fp += (size_t)TT * DD;
  float* h    = fp; fp += (size_t)TT * DD;
  float* gh1  = fp; fp += (size_t)TT * 2 * FF;      // f32, layer-1 experts
  float* go   = fp; fp += (size_t)TT * 2 * DD;
  float* glog = fp; fp += (size_t)TT * EE;
  float* tw   = fp; fp += (size_t)TT * 2;
  int* tidx   = (int*)fp; fp += TT * 2;
  int* rows   = (int*)fp; fp += TT * 2;
  int* gtok   = (int*)fp; fp += TT * 2;
  int* counts = (int*)fp; fp += 16;
  int* cursor = (int*)fp; fp += 16;
  int* bases  = (int*)fp; fp += 16;
  unsigned short* hb   = (unsigned short*)fp; fp += (size_t)TT * DD / 2;
  unsigned short* gh1b = (unsigned short*)fp; fp += (size_t)TT * 2 * FF / 2;
  unsigned short* w1t  = (unsigned short*)fp; fp += (size_t)EE * DD * FF / 2;  // layer-2 only
  unsigned short* w2t  = (unsigned short*)fp; fp += (size_t)EE * FF * DD / 2;
  // total ~51.2M floats < 65.5M

  // final-rmsnorm bf16 activations must survive lm_head -> d_ws (3.1 MB)
  unsigned short* hf = (unsigned short*)d_ws;

  // ---- pre-pass: embed + layer-2 expert weight transposes ----
  k_embed<<<TT, 256, 0, stream>>>(tok, emb, pos, x);
  k_tcvt<<<dim3(96, 24, EE), 256, 0, stream>>>(w1 + (size_t)1 * EE * DD * FF, w1t,
      DD, FF, (size_t)DD * FF, (size_t)DD * FF);
  k_tcvt<<<dim3(24, 96, EE), 256, 0, stream>>>(w2 + (size_t)1 * EE * FF * DD, w2t,
      FF, DD, (size_t)FF * DD, (size_t)FF * DD);

  for (int l = 0; l < NLAYER; l++) {
    const float* wq_l = wq + (size_t)l * DD * DD;
    const float* wk_l = wk + (size_t)l * DD * DD;
    const float* wv_l = wv + (size_t)l * DD * DD;
    const float* wo_l = wo + (size_t)l * DD * DD;
    const float* bq_l = bq + (size_t)l * DD;
    const float* bk_l = bk + (size_t)l * DD;
    const float* bv_l = bvv + (size_t)l * DD;
    const float* bo_l = bo + (size_t)l * DD;

    // attention block (f32 — feeds routers)
    k_rmsnorm<<<TT, 256, 0, stream>>>(x, ln1 + (size_t)l * DD, h, hb);
    k_proj<false><<<dim3(18, 16), 256, 0, stream>>>(h, wq_l, wk_l, wv_l,
        bq_l, bk_l, bv_l, qb, kb, vb, DD, DD);
    k_attn<<<dim3(SS / QBLK, HH, BB), 256, 0, stream>>>(qb, kb, vb, ao);
    k_proj<true><<<dim3(6, 16), 256, 0, stream>>>(ao, wo_l, wo_l, wo_l,
        bo_l, bo_l, bo_l, x, x, x, DD, DD);

    // MoE block
    k_rmsnorm<<<TT, 256, 0, stream>>>(x, ln2 + (size_t)l * DD, h, hb);
    k_gate<<<TT, 256, 0, stream>>>(h, gw + (size_t)l * DD * EE, gb + (size_t)l * EE, glog);
    k_zero<<<1, 64, 0, stream>>>(counts, cursor);
    k_router<<<TT / 256, 256, 0, stream>>>(glog, tidx, tw, counts);
    k_scan<<<1, 1, 0, stream>>>(counts, bases, cursor);
    k_assign<<<TT / 256, 256, 0, stream>>>(tidx, cursor, rows, gtok);
    if (l < NLAYER - 1) {
      // feeds next layer's router -> f32 experts
      k_expert1<<<dim3(FF / 128, TT / 128, EE), 256, 0, stream>>>(
          h, w1 + (size_t)l * EE * DD * FF, b1 + (size_t)l * EE * FF,
          gtok, counts, bases, gh1);
      k_expert2<<<dim3(DD / 128, TT / 128, EE), 256, 0, stream>>>(
          gh1, w2 + (size_t)l * EE * FF * DD, b2 + (size_t)l * EE * DD,
          counts, bases, go);
    } else {
      // last layer: routing-irrelevant -> bf16 MFMA
      k_mfma<true, true, true, 2, false><<<dim3(FF / 128, TT / 128, EE), 256, 0, stream>>>(
          hb, w1t, b1 + (size_t)l * EE * FF, gh1b,
          TT, FF, DD, gtok, counts, bases);
      k_mfma<true, false, true, 0, false><<<dim3(DD / 128, TT / 128, EE), 256, 0, stream>>>(
          gh1b, w2t, b2 + (size_t)l * EE * DD, go,
          TT, DD, FF, gtok, counts, bases);
    }
    k_scatter<<<TT, 256, 0, stream>>>(go, rows, tw, x);
  }

  // final norm + lm_head (bf16 MFMA; B staged from f32 emb in-kernel)
  k_rmsnorm<<<TT, 256, 0, stream>>>(x, lnf, h, hf);
  k_mfma<false, false, false, 0, true><<<dim3(VV / 128, TT / 128), 256, 0, stream>>>(
      hf, emb, nullptr, (float*)d_out,
      TT, VV, DD, nullptr, nullptr, nullptr);
}

// Round 5
// 2329.009 us; speedup vs baseline: 1.8669x; 1.1900x over previous
//
#include <hip/hip_runtime.h>
#include <math.h>

#define TT 2048      // B*S tokens
#define BB 2
#define SS 1024
#define DD 768
#define HH 12
#define FF 3072
#define EE 8
#define VV 32000
#define NLAYER 2
#define QBLK 8

typedef __attribute__((ext_vector_type(8))) short bf16x8;
typedef __attribute__((ext_vector_type(4))) float f32x4;

static __device__ __forceinline__ unsigned short f2b(float f) {
  unsigned u = __float_as_uint(f);
  unsigned r = (u + 0x7fffu + ((u >> 16) & 1u)) >> 16;
  return (unsigned short)r;
}
static __device__ __forceinline__ unsigned int pk2(float a, float b) {
  return (unsigned int)f2b(a) | ((unsigned int)f2b(b) << 16);
}

// ---------------- embedding: x = emb[tok] + pos ----------------
__global__ __launch_bounds__(256) void k_embed(const int* __restrict__ tok,
    const float* __restrict__ emb, const float* __restrict__ pos,
    float* __restrict__ x) {
  int t = blockIdx.x;
  int s = t & (SS - 1);
  int tk = tok[t];
  const float* er = emb + (size_t)tk * DD;
  const float* pr = pos + (size_t)s * DD;
  float* xr = x + (size_t)t * DD;
  for (int d = threadIdx.x; d < DD; d += 256)
    xr[d] = er[d] + pr[d];
}

// ------------- rmsnorm: writes f32 out AND bf16 out -------------
__global__ __launch_bounds__(256) void k_rmsnorm(const float* __restrict__ x,
    const float* __restrict__ w, float* __restrict__ out,
    unsigned short* __restrict__ outb) {
  int t = blockIdx.x;
  const float* xr = x + (size_t)t * DD;
  int tid = threadIdx.x;
  float v0 = xr[tid], v1 = xr[tid + 256], v2 = xr[tid + 512];
  float ss = v0 * v0 + v1 * v1 + v2 * v2;
  for (int off = 32; off > 0; off >>= 1) ss += __shfl_down(ss, off, 64);
  __shared__ float ps[4];
  int wid = tid >> 6, lane = tid & 63;
  if (lane == 0) ps[wid] = ss;
  __syncthreads();
  float r = rsqrtf((ps[0] + ps[1] + ps[2] + ps[3]) * (1.0f / DD) + 1e-6f);
  float* orow = out + (size_t)t * DD;
  unsigned short* brow = outb + (size_t)t * DD;
  float o0 = v0 * r * w[tid], o1 = v1 * r * w[tid + 256], o2 = v2 * r * w[tid + 512];
  orow[tid] = o0; orow[tid + 256] = o1; orow[tid + 512] = o2;
  brow[tid] = f2b(o0); brow[tid + 256] = f2b(o1); brow[tid + 512] = f2b(o2);
}

// ------------- transpose+convert: f32 [R][C] -> bf16 [C][R] -------------
__global__ __launch_bounds__(256) void k_tcvt(const float* __restrict__ src,
    unsigned short* __restrict__ dst, int R, int C, size_t srcZ, size_t dstZ) {
  src += (size_t)blockIdx.z * srcZ;
  dst += (size_t)blockIdx.z * dstZ;
  __shared__ unsigned short tile[32][40];
  int t = threadIdx.x;
  int r = t >> 3, c4 = (t & 7) * 4;
  int r0 = blockIdx.y * 32, c0 = blockIdx.x * 32;
  float4 v = *(const float4*)(src + (size_t)(r0 + r) * C + c0 + c4);
  tile[r][c4 + 0] = f2b(v.x); tile[r][c4 + 1] = f2b(v.y);
  tile[r][c4 + 2] = f2b(v.z); tile[r][c4 + 3] = f2b(v.w);
  __syncthreads();
  int cc = t >> 3, r4 = (t & 7) * 4;
  ushort4 o;
  o.x = tile[r4 + 0][cc]; o.y = tile[r4 + 1][cc];
  o.z = tile[r4 + 2][cc]; o.w = tile[r4 + 3][cc];
  *(ushort4*)(dst + (size_t)(c0 + cc) * R + r0 + r4) = o;
}

// ------------- straight convert f32 -> bf16 (same layout) -------------
__global__ __launch_bounds__(256) void k_cvt(const float* __restrict__ src,
    unsigned short* __restrict__ dst) {
  size_t i = ((size_t)blockIdx.x * 256 + threadIdx.x) * 8;
  float4 a = *(const float4*)(src + i);
  float4 b = *(const float4*)(src + i + 4);
  ushort4 o0, o1;
  o0.x = f2b(a.x); o0.y = f2b(a.y); o0.z = f2b(a.z); o0.w = f2b(a.w);
  o1.x = f2b(b.x); o1.y = f2b(b.y); o1.z = f2b(b.z); o1.w = f2b(b.w);
  *(ushort4*)(dst + i) = o0;
  *(ushort4*)(dst + i + 4) = o1;
}

// ======== f32 split-K 128x128 GEMM (router-feeding path), no bias ========
// dense:  z = split idx; n-tiles span up to 3 column-thirds (W0/W1/W2)
// expert: z = e*nsplit + s; rows gathered-contiguous per expert
template<bool EXPERT>
__global__ __launch_bounds__(256) void k_skf32(
    const float* __restrict__ A, const float* __restrict__ W0,
    const float* __restrict__ W1, const float* __restrict__ W2,
    float* __restrict__ part, int M, int Ntot, int Nthird, int K, int KC,
    int nsplit, int prows,
    const int* __restrict__ counts, const int* __restrict__ bases) {
  int s, base = 0, cnt = M, sel = 0, n0;
  const float* W;
  if (EXPERT) {
    int z = blockIdx.z;
    s = z % nsplit;
    int e = z / nsplit;
    cnt = counts[e]; base = bases[e];
    W = W0 + (size_t)e * K * Nthird;
    n0 = blockIdx.x * 128;
  } else {
    s = blockIdx.z;
    int tpn = Nthird >> 7;
    sel = blockIdx.x / tpn;
    n0 = (blockIdx.x - sel * tpn) * 128;
    W = sel == 0 ? W0 : sel == 1 ? W1 : W2;
  }
  int m0 = blockIdx.y * 128;
  if (EXPERT && m0 >= cnt) return;
  int kbase = s * KC;

  __shared__ float As[128][17];
  __shared__ float Bs[16][136];
  int tid = threadIdx.x;
  int tx = tid & 15, ty = tid >> 4;
  int ra = tid >> 1, ka0 = (tid & 1) * 8;
  int kb = tid >> 4, nb0 = (tid & 15) * 8;
  bool arow_ok = !EXPERT || (m0 + ra < cnt);
  const float* Arow = A + (size_t)(EXPERT ? (base + m0 + (arow_ok ? ra : 0))
                                          : (m0 + ra)) * K + kbase;
  float acc[8][8] = {};
  for (int k0 = 0; k0 < KC; k0 += 16) {
    float4 av0 = make_float4(0.f, 0.f, 0.f, 0.f), av1 = av0;
    if (arow_ok) {
      av0 = *(const float4*)(Arow + k0 + ka0);
      av1 = *(const float4*)(Arow + k0 + ka0 + 4);
    }
    As[ra][ka0 + 0] = av0.x; As[ra][ka0 + 1] = av0.y;
    As[ra][ka0 + 2] = av0.z; As[ra][ka0 + 3] = av0.w;
    As[ra][ka0 + 4] = av1.x; As[ra][ka0 + 5] = av1.y;
    As[ra][ka0 + 6] = av1.z; As[ra][ka0 + 7] = av1.w;
    const float* Wrow = W + (size_t)(kbase + k0 + kb) * Nthird + n0 + nb0;
    float4 bv0 = *(const float4*)(Wrow);
    float4 bv1 = *(const float4*)(Wrow + 4);
    Bs[kb][nb0 + 0] = bv0.x; Bs[kb][nb0 + 1] = bv0.y;
    Bs[kb][nb0 + 2] = bv0.z; Bs[kb][nb0 + 3] = bv0.w;
    Bs[kb][nb0 + 4] = bv1.x; Bs[kb][nb0 + 5] = bv1.y;
    Bs[kb][nb0 + 6] = bv1.z; Bs[kb][nb0 + 7] = bv1.w;
    __syncthreads();
#pragma unroll
    for (int kk = 0; kk < 16; kk++) {
      float a[8], b[8];
#pragma unroll
      for (int i = 0; i < 8; i++) a[i] = As[ty * 8 + i][kk];
#pragma unroll
      for (int j = 0; j < 8; j++) b[j] = Bs[kk][tx * 8 + j];
#pragma unroll
      for (int i = 0; i < 8; i++) {
#pragma unroll
        for (int j = 0; j < 8; j++) acc[i][j] = fmaf(a[i], b[j], acc[i][j]);
      }
    }
    __syncthreads();
  }
#pragma unroll
  for (int i = 0; i < 8; i++) {
    int m = m0 + ty * 8 + i;
    if (EXPERT && m >= cnt) continue;
    size_t prow = EXPERT ? ((size_t)s * prows + base + m) : ((size_t)s * M + m);
    float* orow = part + prow * Ntot + sel * Nthird;
#pragma unroll
    for (int j = 0; j < 8; j++)
      orow[n0 + tx * 8 + j] = acc[i][j];
  }
}

// ---- QKV reduce: q/k/v = part0+part1 + bias ----
__global__ __launch_bounds__(256) void k_qkvred(const float* __restrict__ part,
    const float* __restrict__ bq, const float* __restrict__ bk,
    const float* __restrict__ bv, float* __restrict__ qb,
    float* __restrict__ kb, float* __restrict__ vb) {
  int t = blockIdx.x;
  for (int c = threadIdx.x; c < 2304; c += 256) {
    float v = part[(size_t)t * 2304 + c] + part[((size_t)TT + t) * 2304 + c];
    if (c < 768)       qb[(size_t)t * DD + c] = v + bq[c];
    else if (c < 1536) kb[(size_t)t * DD + c - 768] = v + bk[c - 768];
    else               vb[(size_t)t * DD + c - 1536] = v + bv[c - 1536];
  }
}

// ---- O-proj reduce: x += sum(part[0..3]) + bo ----
__global__ __launch_bounds__(256) void k_ored(const float* __restrict__ part,
    const float* __restrict__ bo, float* __restrict__ x) {
  int t = blockIdx.x;
  for (int d = threadIdx.x; d < DD; d += 256) {
    float v = part[(size_t)t * DD + d]
            + part[((size_t)TT + t) * DD + d]
            + part[((size_t)2 * TT + t) * DD + d]
            + part[((size_t)3 * TT + t) * DD + d];
    x[(size_t)t * DD + d] += v + bo[d];
  }
}

// ---- expert2 reduce + gate-weighted scatter: x += w*(sum(part)+b2) ----
__global__ __launch_bounds__(256) void k_e2red(const float* __restrict__ part,
    const int* __restrict__ rows, const int* __restrict__ tidx,
    const float* __restrict__ tw, const float* __restrict__ b2,
    float* __restrict__ x) {
  int t = blockIdx.x;
  int r0 = rows[t * 2], r1 = rows[t * 2 + 1];
  int e0 = tidx[t * 2], e1 = tidx[t * 2 + 1];
  float w0 = tw[t * 2], w1 = tw[t * 2 + 1];
  for (int d = threadIdx.x; d < DD; d += 256) {
    float v0 = part[(size_t)r0 * DD + d]
             + part[((size_t)4096 + r0) * DD + d]
             + part[((size_t)8192 + r0) * DD + d]
             + part[((size_t)12288 + r0) * DD + d] + b2[e0 * DD + d];
    float v1 = part[(size_t)r1 * DD + d]
             + part[((size_t)4096 + r1) * DD + d]
             + part[((size_t)8192 + r1) * DD + d]
             + part[((size_t)12288 + r1) * DD + d] + b2[e1 * DD + d];
    x[(size_t)t * DD + d] += w0 * v0 + w1 * v1;
  }
}

// ---------------- attention (f32, separate q/k/v) ----------------
__global__ __launch_bounds__(256) void k_attn(const float* __restrict__ q,
    const float* __restrict__ k, const float* __restrict__ v, float* __restrict__ ao) {
  int b = blockIdx.z, hh = blockIdx.y, q0 = blockIdx.x * QBLK;
  __shared__ float qs[QBLK][64];
  __shared__ float sc[QBLK][SS];
  __shared__ float red[QBLK][8];
  int tid = threadIdx.x;
  const size_t hoff = (size_t)b * SS * DD + (size_t)hh * 64;
  for (int i = tid; i < QBLK * 64; i += 256) {
    int qi = i >> 6, d = i & 63;
    qs[qi][d] = q[hoff + (size_t)(q0 + qi) * DD + d];
  }
  __syncthreads();
  int kmax = q0 + QBLK;
  for (int j = tid; j < kmax; j += 256) {
    const float* kr = k + hoff + (size_t)j * DD;
    float p[QBLK];
#pragma unroll
    for (int qi = 0; qi < QBLK; qi++) p[qi] = 0.f;
#pragma unroll 4
    for (int c = 0; c < 16; c++) {
      float4 kv = *(const float4*)(kr + c * 4);
#pragma unroll
      for (int qi = 0; qi < QBLK; qi++)
        p[qi] += qs[qi][c * 4] * kv.x + qs[qi][c * 4 + 1] * kv.y +
                 qs[qi][c * 4 + 2] * kv.z + qs[qi][c * 4 + 3] * kv.w;
    }
#pragma unroll
    for (int qi = 0; qi < QBLK; qi++)
      sc[qi][j] = (j <= q0 + qi) ? p[qi] * 0.125f : -1e30f;
  }
  __syncthreads();
  int wid = tid >> 6, lane = tid & 63;
#pragma unroll
  for (int qi = 0; qi < QBLK; qi++) {
    float mx = -1e30f;
    for (int j = tid; j < kmax; j += 256) mx = fmaxf(mx, sc[qi][j]);
    for (int off = 32; off > 0; off >>= 1) mx = fmaxf(mx, __shfl_down(mx, off, 64));
    if (lane == 0) red[qi][wid] = mx;
  }
  __syncthreads();
#pragma unroll
  for (int qi = 0; qi < QBLK; qi++) {
    float mx = fmaxf(fmaxf(red[qi][0], red[qi][1]), fmaxf(red[qi][2], red[qi][3]));
    float s = 0.f;
    for (int j = tid; j < kmax; j += 256) {
      float e = __expf(sc[qi][j] - mx);
      sc[qi][j] = e;
      s += e;
    }
    for (int off = 32; off > 0; off >>= 1) s += __shfl_down(s, off, 64);
    if (lane == 0) red[qi][4 + wid] = s;
  }
  __syncthreads();
  int d = tid & 63, g = tid >> 6;
  for (int qi = g; qi < QBLK; qi += 4) {
    float inv = 1.f / (red[qi][4] + red[qi][5] + red[qi][6] + red[qi][7]);
    float acc = 0.f;
    int jend = q0 + qi + 1;
    const float* vp = v + hoff + d;
    for (int j = 0; j < jend; j++) acc = fmaf(sc[qi][j], vp[(size_t)j * DD], acc);
    ao[hoff + (size_t)(q0 + qi) * DD + d] = acc * inv;
  }
}

// ---------------- gate logits ----------------
__global__ __launch_bounds__(256) void k_gate(const float* __restrict__ h,
    const float* __restrict__ gw, const float* __restrict__ gb,
    float* __restrict__ glog) {
  __shared__ float hr[DD];
  int t = blockIdx.x;
  for (int d = threadIdx.x; d < DD; d += 256) hr[d] = h[(size_t)t * DD + d];
  __syncthreads();
  int e = threadIdx.x >> 5, j = threadIdx.x & 31;
  float s = 0.f;
  for (int d = j; d < DD; d += 32) s += hr[d] * gw[d * EE + e];
  for (int off = 16; off > 0; off >>= 1) s += __shfl_down(s, off, 32);
  if (j == 0) glog[t * EE + e] = s + gb[e];
}

// ---------------- router ----------------
__global__ void k_zero(int* counts, int* cursor) {
  int i = threadIdx.x;
  if (i < EE) { counts[i] = 0; cursor[i] = 0; }
}

__global__ void k_router(const float* __restrict__ glog, int* __restrict__ tidx,
    float* __restrict__ tw, int* __restrict__ counts) {
  int t = blockIdx.x * 256 + threadIdx.x;
  if (t >= TT) return;
  float l[EE];
#pragma unroll
  for (int e = 0; e < EE; e++) l[e] = glog[t * EE + e];
  int i0 = 0; float v0 = l[0];
#pragma unroll
  for (int e = 1; e < EE; e++) if (l[e] > v0) { v0 = l[e]; i0 = e; }
  int i1 = -1; float v1 = -1e30f;
#pragma unroll
  for (int e = 0; e < EE; e++) if (e != i0 && l[e] > v1) { v1 = l[e]; i1 = e; }
  float e1 = __expf(v1 - v0);
  float inv = 1.f / (1.f + e1);
  tw[t * 2] = inv; tw[t * 2 + 1] = e1 * inv;
  tidx[t * 2] = i0; tidx[t * 2 + 1] = i1;
  atomicAdd(&counts[i0], 1);
  atomicAdd(&counts[i1], 1);
}

__global__ void k_scan(const int* __restrict__ counts, int* __restrict__ bases,
                       int* __restrict__ cursor) {
  int b = 0;
  for (int e = 0; e < EE; e++) { bases[e] = b; cursor[e] = b; b += counts[e]; }
}

__global__ void k_assign(const int* __restrict__ tidx, int* __restrict__ cursor,
                         int* __restrict__ rows, int* __restrict__ gtok) {
  int t = blockIdx.x * 256 + threadIdx.x;
  if (t >= TT) return;
#pragma unroll
  for (int kk = 0; kk < 2; kk++) {
    int e = tidx[t * 2 + kk];
    int r = atomicAdd(&cursor[e], 1);
    rows[t * 2 + kk] = r;
    gtok[r] = t;
  }
}

// ---------------- f32 expert FFN1 (layer feeding a router) ----------------
__global__ __launch_bounds__(256) void k_expert1(const float* __restrict__ h,
    const float* __restrict__ w1, const float* __restrict__ b1,
    const int* __restrict__ gtok, const int* __restrict__ counts,
    const int* __restrict__ bases, float* __restrict__ gh1) {
  int e = blockIdx.z;
  int cnt = counts[e];
  int m0 = blockIdx.y * 128;
  if (m0 >= cnt) return;
  int base = bases[e];
  int n0 = blockIdx.x * 128;
  const float* W = w1 + (size_t)e * DD * FF;
  __shared__ float As[128][17];
  __shared__ float Bs[16][136];
  int tid = threadIdx.x;
  int tx = tid & 15, ty = tid >> 4;
  int ra = tid >> 1, ka0 = (tid & 1) * 8;
  int kb = tid >> 4, nb0 = (tid & 15) * 8;
  int tok = (m0 + ra < cnt) ? gtok[base + m0 + ra] : -1;
  const float* Arow = h + (size_t)(tok < 0 ? 0 : tok) * DD;
  float acc[8][8] = {};
  for (int k0 = 0; k0 < DD; k0 += 16) {
    float4 av0 = make_float4(0.f, 0.f, 0.f, 0.f), av1 = av0;
    if (tok >= 0) {
      av0 = *(const float4*)(Arow + k0 + ka0);
      av1 = *(const float4*)(Arow + k0 + ka0 + 4);
    }
    As[ra][ka0 + 0] = av0.x; As[ra][ka0 + 1] = av0.y;
    As[ra][ka0 + 2] = av0.z; As[ra][ka0 + 3] = av0.w;
    As[ra][ka0 + 4] = av1.x; As[ra][ka0 + 5] = av1.y;
    As[ra][ka0 + 6] = av1.z; As[ra][ka0 + 7] = av1.w;
    float4 bv0 = *(const float4*)(W + (size_t)(k0 + kb) * FF + n0 + nb0);
    float4 bv1 = *(const float4*)(W + (size_t)(k0 + kb) * FF + n0 + nb0 + 4);
    Bs[kb][nb0 + 0] = bv0.x; Bs[kb][nb0 + 1] = bv0.y;
    Bs[kb][nb0 + 2] = bv0.z; Bs[kb][nb0 + 3] = bv0.w;
    Bs[kb][nb0 + 4] = bv1.x; Bs[kb][nb0 + 5] = bv1.y;
    Bs[kb][nb0 + 6] = bv1.z; Bs[kb][nb0 + 7] = bv1.w;
    __syncthreads();
#pragma unroll
    for (int kk = 0; kk < 16; kk++) {
      float a[8], b[8];
#pragma unroll
      for (int i = 0; i < 8; i++) a[i] = As[ty * 8 + i][kk];
#pragma unroll
      for (int j = 0; j < 8; j++) b[j] = Bs[kk][tx * 8 + j];
#pragma unroll
      for (int i = 0; i < 8; i++) {
#pragma unroll
        for (int j = 0; j < 8; j++) acc[i][j] = fmaf(a[i], b[j], acc[i][j]);
      }
    }
    __syncthreads();
  }
#pragma unroll
  for (int i = 0; i < 8; i++) {
    int m = m0 + ty * 8 + i;
    if (m >= cnt) continue;
    float* orow = gh1 + (size_t)(base + m) * FF;
#pragma unroll
    for (int j = 0; j < 8; j++) {
      int n = n0 + tx * 8 + j;
      float vv = acc[i][j] + b1[e * FF + n];
      orow[n] = 0.5f * vv * (1.f + erff(vv * 0.70710678118654752f));
    }
  }
}

// =============== bf16 MFMA GEMM (routing-irrelevant work only) ===============
// EPI: 0 = store f32 (+bias), 2 = gelu -> bf16 (+bias). BF32: stage B from f32.
template<bool EXPERT, bool GATHER, bool BIAS, int EPI, bool BF32>
__global__ __launch_bounds__(256) void k_mfma(
    const unsigned short* __restrict__ A, const void* __restrict__ Bt,
    const float* __restrict__ bias, void* __restrict__ Cv,
    int M, int N, int K,
    const int* __restrict__ gtok, const int* __restrict__ counts,
    const int* __restrict__ bases) {
  int cnt = M, base = 0;
  if (EXPERT) {
    int e = blockIdx.z;
    cnt = counts[e]; base = bases[e];
    if (BIAS) bias += (size_t)e * N;
  }
  int m0 = blockIdx.y * 128;
  if (EXPERT && m0 >= cnt) return;
  int n0 = blockIdx.x * 128;

  __shared__ unsigned short As[128 * 40];
  __shared__ unsigned short Bs[128 * 40];

  int tid = threadIdx.x;
  int srow = tid >> 1;            // 0..127
  int scol = (tid & 1) * 16;      // 0 or 16 (elements)

  bool avalid = true;
  const unsigned short* arow;
  if (GATHER) {
    avalid = (m0 + srow) < cnt;
    int tk = avalid ? gtok[base + m0 + srow] : 0;
    arow = A + (size_t)tk * K + scol;
  } else if (EXPERT) {
    avalid = (m0 + srow) < cnt;
    arow = A + (size_t)(base + m0 + (avalid ? srow : 0)) * K + scol;
  } else {
    arow = A + (size_t)(m0 + srow) * K + scol;
  }

  const unsigned short* brow16 = nullptr;
  const float* browf = nullptr;
  if (BF32) {
    browf = (const float*)Bt + (size_t)(n0 + srow) * K + scol;
  } else {
    const unsigned short* B16 = (const unsigned short*)Bt;
    if (EXPERT) B16 += (size_t)blockIdx.z * N * K;
    brow16 = B16 + (size_t)(n0 + srow) * K + scol;
  }

  unsigned short* As_w = As + srow * 40 + scol;
  unsigned short* Bs_w = Bs + srow * 40 + scol;

  int lane = tid & 63, wid = tid >> 6;
  int wr = wid >> 1, wc = wid & 1;
  int l15 = lane & 15, lg = lane >> 4;
  const unsigned short* Ar = As + ((wr * 64 + l15) * 40 + lg * 8);
  const unsigned short* Br = Bs + ((wc * 64 + l15) * 40 + lg * 8);

  f32x4 acc[4][4];
#pragma unroll
  for (int i = 0; i < 4; i++)
#pragma unroll
    for (int j = 0; j < 4; j++) acc[i][j] = (f32x4){0.f, 0.f, 0.f, 0.f};

  for (int k0 = 0; k0 < K; k0 += 32) {
    uint4 av0 = {0, 0, 0, 0}, av1 = {0, 0, 0, 0};
    if (avalid) {
      av0 = *(const uint4*)(arow + k0);
      av1 = *(const uint4*)(arow + k0 + 8);
    }
    uint4 bv0, bv1;
    if (BF32) {
      float4 f0 = *(const float4*)(browf + k0);
      float4 f1 = *(const float4*)(browf + k0 + 4);
      float4 f2 = *(const float4*)(browf + k0 + 8);
      float4 f3 = *(const float4*)(browf + k0 + 12);
      bv0 = make_uint4(pk2(f0.x, f0.y), pk2(f0.z, f0.w), pk2(f1.x, f1.y), pk2(f1.z, f1.w));
      bv1 = make_uint4(pk2(f2.x, f2.y), pk2(f2.z, f2.w), pk2(f3.x, f3.y), pk2(f3.z, f3.w));
    } else {
      bv0 = *(const uint4*)(brow16 + k0);
      bv1 = *(const uint4*)(brow16 + k0 + 8);
    }
    *(uint4*)As_w = av0; *(uint4*)(As_w + 8) = av1;
    *(uint4*)Bs_w = bv0; *(uint4*)(Bs_w + 8) = bv1;
    __syncthreads();
    bf16x8 af[4], bfr[4];
#pragma unroll
    for (int f = 0; f < 4; f++) {
      af[f]  = *(const bf16x8*)(Ar + f * 640);
      bfr[f] = *(const bf16x8*)(Br + f * 640);
    }
#pragma unroll
    for (int i = 0; i < 4; i++)
#pragma unroll
      for (int j = 0; j < 4; j++)
        acc[i][j] = __builtin_amdgcn_mfma_f32_16x16x32_bf16(af[i], bfr[j], acc[i][j], 0, 0, 0);
    __syncthreads();
  }

#pragma unroll
  for (int j = 0; j < 4; j++) {
    int n = n0 + wc * 64 + j * 16 + l15;
    float bb = BIAS ? bias[n] : 0.f;
#pragma unroll
    for (int i = 0; i < 4; i++) {
      int mb = m0 + wr * 64 + i * 16 + lg * 4;
#pragma unroll
      for (int r = 0; r < 4; r++) {
        int m = mb + r;
        if (EXPERT && m >= cnt) continue;
        size_t off = (size_t)(base + m) * N + n;
        float v = acc[i][j][r] + bb;
        if (EPI == 0) {
          ((float*)Cv)[off] = v;
        } else {
          float g = 0.5f * v * (1.f + erff(v * 0.70710678118654752f));
          ((unsigned short*)Cv)[off] = f2b(g);
        }
      }
    }
  }
}

// ---------------- MoE scatter (bf16 path): x += w0*go[r0] + w1*go[r1] ----------------
__global__ __launch_bounds__(256) void k_scatter(const float* __restrict__ go,
    const int* __restrict__ rows, const float* __restrict__ tw, float* __restrict__ x) {
  int t = blockIdx.x;
  int r0 = rows[t * 2], r1 = rows[t * 2 + 1];
  float w0 = tw[t * 2], w1 = tw[t * 2 + 1];
  float* xr = x + (size_t)t * DD;
  const float* g0 = go + (size_t)r0 * DD;
  const float* g1 = go + (size_t)r1 * DD;
  for (int d = threadIdx.x; d < DD; d += 256)
    xr[d] += w0 * g0[d] + w1 * g1[d];
}

// ================= host =================
extern "C" void kernel_launch(void* const* d_in, const int* in_sizes, int n_in,
                              void* d_out, int out_size, void* d_ws, size_t ws_size,
                              hipStream_t stream) {
  (void)in_sizes; (void)n_in; (void)out_size;
  const int* tok   = (const int*)d_in[0];
  const float* emb = (const float*)d_in[1];
  const float* pos = (const float*)d_in[2];
  const float* wq  = (const float*)d_in[3];
  const float* bq  = (const float*)d_in[4];
  const float* wk  = (const float*)d_in[5];
  const float* bk  = (const float*)d_in[6];
  const float* wv  = (const float*)d_in[7];
  const float* bvv = (const float*)d_in[8];
  const float* wo  = (const float*)d_in[9];
  const float* bo  = (const float*)d_in[10];
  const float* ln1 = (const float*)d_in[11];
  const float* ln2 = (const float*)d_in[12];
  const float* gw  = (const float*)d_in[13];
  const float* gb  = (const float*)d_in[14];
  const float* w1  = (const float*)d_in[15];
  const float* b1  = (const float*)d_in[16];
  const float* w2  = (const float*)d_in[17];
  const float* b2  = (const float*)d_in[18];
  const float* lnf = (const float*)d_in[19];

  // ---- scratch carved from d_out (65.5M f32; all dead before lm_head) ----
  float* fp = (float*)d_out;
  float* qb   = fp; fp += (size_t)TT * DD;
  float* kb   = fp; fp += (size_t)TT * DD;
  float* vb   = fp; fp += (size_t)TT * DD;
  float* ao   = fp; fp += (size_t)TT * DD;
  float* x    = fp; fp += (size_t)TT * DD;
  float* h    = fp; fp += (size_t)TT * DD;
  float* gh1  = fp; fp += (size_t)TT * 2 * FF;      // f32, layer-1 experts
  float* go   = fp; fp += (size_t)TT * 2 * DD;
  float* glog = fp; fp += (size_t)TT * EE;
  float* tw   = fp; fp += (size_t)TT * 2;
  int* tidx   = (int*)fp; fp += TT * 2;
  int* rows   = (int*)fp; fp += TT * 2;
  int* gtok   = (int*)fp; fp += TT * 2;
  int* counts = (int*)fp; fp += 16;
  int* cursor = (int*)fp; fp += 16;
  int* bases  = (int*)fp; fp += 16;
  unsigned short* hb   = (unsigned short*)fp; fp += (size_t)TT * DD / 2;
  unsigned short* gh1b = (unsigned short*)fp; fp += (size_t)TT * 2 * FF / 2;
  unsigned short* w1t  = (unsigned short*)fp; fp += (size_t)EE * DD * FF / 2;  // layer-2 only
  unsigned short* w2t  = (unsigned short*)fp; fp += (size_t)EE * FF * DD / 2;
  float* part = fp; fp += (size_t)4 * 4096 * DD;    // split-K partials, 12.58M
  // total ~63.8M floats < 65.5M

  // d_ws: hf (bf16 final activations, must survive lm_head) + optional embT
  unsigned short* hf = (unsigned short*)d_ws;
  unsigned short* embT = (unsigned short*)d_ws + (size_t)TT * DD;
  bool useEmbT = ws_size >= (size_t)TT * DD * 2 + (size_t)VV * DD * 2;

  // ---- pre-pass ----
  k_embed<<<TT, 256, 0, stream>>>(tok, emb, pos, x);
  k_tcvt<<<dim3(96, 24, EE), 256, 0, stream>>>(w1 + (size_t)1 * EE * DD * FF, w1t,
      DD, FF, (size_t)DD * FF, (size_t)DD * FF);
  k_tcvt<<<dim3(24, 96, EE), 256, 0, stream>>>(w2 + (size_t)1 * EE * FF * DD, w2t,
      FF, DD, (size_t)FF * DD, (size_t)FF * DD);
  if (useEmbT)
    k_cvt<<<(VV * DD) / (256 * 8), 256, 0, stream>>>(emb, embT);

  for (int l = 0; l < NLAYER; l++) {
    const float* wq_l = wq + (size_t)l * DD * DD;
    const float* wk_l = wk + (size_t)l * DD * DD;
    const float* wv_l = wv + (size_t)l * DD * DD;
    const float* wo_l = wo + (size_t)l * DD * DD;

    // attention block (f32 — feeds routers)
    k_rmsnorm<<<TT, 256, 0, stream>>>(x, ln1 + (size_t)l * DD, h, hb);
    // QKV: split-K=2, 3 column-thirds
    k_skf32<false><<<dim3(18, 16, 2), 256, 0, stream>>>(h, wq_l, wk_l, wv_l,
        part, TT, 2304, 768, 768, 384, 2, TT, nullptr, nullptr);
    k_qkvred<<<TT, 256, 0, stream>>>(part, bq + (size_t)l * DD, bk + (size_t)l * DD,
        bvv + (size_t)l * DD, qb, kb, vb);
    k_attn<<<dim3(SS / QBLK, HH, BB), 256, 0, stream>>>(qb, kb, vb, ao);
    // O-proj: split-K=4
    k_skf32<false><<<dim3(6, 16, 4), 256, 0, stream>>>(ao, wo_l, wo_l, wo_l,
        part, TT, 768, 768, 768, 192, 4, TT, nullptr, nullptr);
    k_ored<<<TT, 256, 0, stream>>>(part, bo + (size_t)l * DD, x);

    // MoE block
    k_rmsnorm<<<TT, 256, 0, stream>>>(x, ln2 + (size_t)l * DD, h, hb);
    k_gate<<<TT, 256, 0, stream>>>(h, gw + (size_t)l * DD * EE, gb + (size_t)l * EE, glog);
    k_zero<<<1, 64, 0, stream>>>(counts, cursor);
    k_router<<<TT / 256, 256, 0, stream>>>(glog, tidx, tw, counts);
    k_scan<<<1, 1, 0, stream>>>(counts, bases, cursor);
    k_assign<<<TT / 256, 256, 0, stream>>>(tidx, cursor, rows, gtok);
    if (l < NLAYER - 1) {
      // feeds next layer's router -> f32 experts
      k_expert1<<<dim3(FF / 128, TT / 128, EE), 256, 0, stream>>>(
          h, w1 + (size_t)l * EE * DD * FF, b1 + (size_t)l * EE * FF,
          gtok, counts, bases, gh1);
      // expert2: split-K=4 over K=FF, then fused reduce+scatter
      k_skf32<true><<<dim3(6, 16, 32), 256, 0, stream>>>(gh1,
          w2 + (size_t)l * EE * FF * DD, nullptr, nullptr,
          part, TT, 768, 768, FF, 768, 4, 4096, counts, bases);
      k_e2red<<<TT, 256, 0, stream>>>(part, rows, tidx, tw,
          b2 + (size_t)l * EE * DD, x);
    } else {
      // last layer: routing-irrelevant -> bf16 MFMA
      k_mfma<true, true, true, 2, false><<<dim3(FF / 128, TT / 128, EE), 256, 0, stream>>>(
          hb, w1t, b1 + (size_t)l * EE * FF, gh1b,
          TT, FF, DD, gtok, counts, bases);
      k_mfma<true, false, true, 0, false><<<dim3(DD / 128, TT / 128, EE), 256, 0, stream>>>(
          gh1b, w2t, b2 + (size_t)l * EE * DD, go,
          TT, DD, FF, gtok, counts, bases);
      k_scatter<<<TT, 256, 0, stream>>>(go, rows, tw, x);
    }
  }

  // final norm + lm_head (bf16 MFMA)
  k_rmsnorm<<<TT, 256, 0, stream>>>(x, lnf, h, hf);
  if (useEmbT) {
    k_mfma<false, false, false, 0, false><<<dim3(VV / 128, TT / 128), 256, 0, stream>>>(
        hf, embT, nullptr, (float*)d_out,
        TT, VV, DD, nullptr, nullptr, nullptr);
  } else {
    k_mfma<false, false, false, 0, true><<<dim3(VV / 128, TT / 128), 256, 0, stream>>>(
        hf, emb, nullptr, (float*)d_out,
        TT, VV, DD, nullptr, nullptr, nullptr);
  }
}

// Round 6
// 2273.500 us; speedup vs baseline: 1.9125x; 1.0244x over previous
//
#include <hip/hip_runtime.h>
#include <math.h>

#define TT 2048      // B*S tokens
#define BB 2
#define SS 1024
#define DD 768
#define HH 12
#define FF 3072
#define EE 8
#define VV 32000
#define NLAYER 2
#define QBLK 8

typedef __attribute__((ext_vector_type(8))) short bf16x8;
typedef __attribute__((ext_vector_type(4))) float f32x4;

static __device__ __forceinline__ unsigned short f2b(float f) {
  unsigned u = __float_as_uint(f);
  unsigned r = (u + 0x7fffu + ((u >> 16) & 1u)) >> 16;
  return (unsigned short)r;
}
static __device__ __forceinline__ unsigned int pk2(float a, float b) {
  return (unsigned int)f2b(a) | ((unsigned int)f2b(b) << 16);
}

// ---------------- embedding: x = emb[tok] + pos ----------------
__global__ __launch_bounds__(256) void k_embed(const int* __restrict__ tok,
    const float* __restrict__ emb, const float* __restrict__ pos,
    float* __restrict__ x) {
  int t = blockIdx.x;
  int s = t & (SS - 1);
  int tk = tok[t];
  const float* er = emb + (size_t)tk * DD;
  const float* pr = pos + (size_t)s * DD;
  float* xr = x + (size_t)t * DD;
  for (int d = threadIdx.x; d < DD; d += 256)
    xr[d] = er[d] + pr[d];
}

// ------------- rmsnorm: writes f32 out AND bf16 out -------------
__global__ __launch_bounds__(256) void k_rmsnorm(const float* __restrict__ x,
    const float* __restrict__ w, float* __restrict__ out,
    unsigned short* __restrict__ outb) {
  int t = blockIdx.x;
  const float* xr = x + (size_t)t * DD;
  int tid = threadIdx.x;
  float v0 = xr[tid], v1 = xr[tid + 256], v2 = xr[tid + 512];
  float ss = v0 * v0 + v1 * v1 + v2 * v2;
  for (int off = 32; off > 0; off >>= 1) ss += __shfl_down(ss, off, 64);
  __shared__ float ps[4];
  int wid = tid >> 6, lane = tid & 63;
  if (lane == 0) ps[wid] = ss;
  __syncthreads();
  float r = rsqrtf((ps[0] + ps[1] + ps[2] + ps[3]) * (1.0f / DD) + 1e-6f);
  float* orow = out + (size_t)t * DD;
  unsigned short* brow = outb + (size_t)t * DD;
  float o0 = v0 * r * w[tid], o1 = v1 * r * w[tid + 256], o2 = v2 * r * w[tid + 512];
  orow[tid] = o0; orow[tid + 256] = o1; orow[tid + 512] = o2;
  brow[tid] = f2b(o0); brow[tid + 256] = f2b(o1); brow[tid + 512] = f2b(o2);
}

// ------------- transpose+convert: f32 [R][C] -> bf16 [C][R] -------------
__global__ __launch_bounds__(256) void k_tcvt(const float* __restrict__ src,
    unsigned short* __restrict__ dst, int R, int C, size_t srcZ, size_t dstZ) {
  src += (size_t)blockIdx.z * srcZ;
  dst += (size_t)blockIdx.z * dstZ;
  __shared__ unsigned short tile[32][40];
  int t = threadIdx.x;
  int r = t >> 3, c4 = (t & 7) * 4;
  int r0 = blockIdx.y * 32, c0 = blockIdx.x * 32;
  float4 v = *(const float4*)(src + (size_t)(r0 + r) * C + c0 + c4);
  tile[r][c4 + 0] = f2b(v.x); tile[r][c4 + 1] = f2b(v.y);
  tile[r][c4 + 2] = f2b(v.z); tile[r][c4 + 3] = f2b(v.w);
  __syncthreads();
  int cc = t >> 3, r4 = (t & 7) * 4;
  ushort4 o;
  o.x = tile[r4 + 0][cc]; o.y = tile[r4 + 1][cc];
  o.z = tile[r4 + 2][cc]; o.w = tile[r4 + 3][cc];
  *(ushort4*)(dst + (size_t)(c0 + cc) * R + r0 + r4) = o;
}

// ------------- straight convert f32 -> bf16 (same layout) -------------
__global__ __launch_bounds__(256) void k_cvt(const float* __restrict__ src,
    unsigned short* __restrict__ dst) {
  size_t i = ((size_t)blockIdx.x * 256 + threadIdx.x) * 8;
  float4 a = *(const float4*)(src + i);
  float4 b = *(const float4*)(src + i + 4);
  ushort4 o0, o1;
  o0.x = f2b(a.x); o0.y = f2b(a.y); o0.z = f2b(a.z); o0.w = f2b(a.w);
  o1.x = f2b(b.x); o1.y = f2b(b.y); o1.z = f2b(b.z); o1.w = f2b(b.w);
  *(ushort4*)(dst + i) = o0;
  *(ushort4*)(dst + i + 4) = o1;
}

// ======== f32 split-K 128x128 GEMM, k-major A in LDS + b128 reads ========
// dense:  z = split idx; n-tiles span up to 3 column-thirds (W0/W1/W2)
// expert: z = e*nsplit + s; rows gathered-contiguous per expert
template<bool EXPERT>
__global__ __launch_bounds__(256) void k_skf32(
    const float* __restrict__ A, const float* __restrict__ W0,
    const float* __restrict__ W1, const float* __restrict__ W2,
    float* __restrict__ part, int M, int Ntot, int Nthird, int K, int KC,
    int nsplit, int prows,
    const int* __restrict__ counts, const int* __restrict__ bases) {
  int s, base = 0, cnt = M, sel = 0, n0;
  const float* W;
  if (EXPERT) {
    int z = blockIdx.z;
    s = z % nsplit;
    int e = z / nsplit;
    cnt = counts[e]; base = bases[e];
    W = W0 + (size_t)e * K * Nthird;
    n0 = blockIdx.x * 128;
  } else {
    s = blockIdx.z;
    int tpn = Nthird >> 7;
    sel = blockIdx.x / tpn;
    n0 = (blockIdx.x - sel * tpn) * 128;
    W = sel == 0 ? W0 : sel == 1 ? W1 : W2;
  }
  int m0 = blockIdx.y * 128;
  if (EXPERT && m0 >= cnt) return;
  int kbase = s * KC;

  __shared__ float As[16][132];   // k-major: As[k][m]
  __shared__ float Bs[16][132];
  int tid = threadIdx.x;
  int tx = tid & 15, ty = tid >> 4;
  int ra = tid >> 1, ka0 = (tid & 1) * 8;
  int kb = tid >> 4, nb0 = (tid & 15) * 8;
  bool arow_ok = !EXPERT || (m0 + ra < cnt);
  const float* Arow = A + (size_t)(EXPERT ? (base + m0 + (arow_ok ? ra : 0))
                                          : (m0 + ra)) * K + kbase;
  float acc[8][8] = {};
  for (int k0 = 0; k0 < KC; k0 += 16) {
    float4 av0 = make_float4(0.f, 0.f, 0.f, 0.f), av1 = av0;
    if (arow_ok) {
      av0 = *(const float4*)(Arow + k0 + ka0);
      av1 = *(const float4*)(Arow + k0 + ka0 + 4);
    }
    // transposed write (2-way bank alias = free)
    As[ka0 + 0][ra] = av0.x; As[ka0 + 1][ra] = av0.y;
    As[ka0 + 2][ra] = av0.z; As[ka0 + 3][ra] = av0.w;
    As[ka0 + 4][ra] = av1.x; As[ka0 + 5][ra] = av1.y;
    As[ka0 + 6][ra] = av1.z; As[ka0 + 7][ra] = av1.w;
    const float* Wrow = W + (size_t)(kbase + k0 + kb) * Nthird + n0 + nb0;
    *(float4*)&Bs[kb][nb0] = *(const float4*)(Wrow);
    *(float4*)&Bs[kb][nb0 + 4] = *(const float4*)(Wrow + 4);
    __syncthreads();
#pragma unroll
    for (int kk = 0; kk < 16; kk++) {
      float4 a0 = *(const float4*)&As[kk][ty * 8];
      float4 a1 = *(const float4*)&As[kk][ty * 8 + 4];
      float4 b0 = *(const float4*)&Bs[kk][tx * 8];
      float4 b1 = *(const float4*)&Bs[kk][tx * 8 + 4];
      float a[8] = {a0.x, a0.y, a0.z, a0.w, a1.x, a1.y, a1.z, a1.w};
      float b[8] = {b0.x, b0.y, b0.z, b0.w, b1.x, b1.y, b1.z, b1.w};
#pragma unroll
      for (int i = 0; i < 8; i++) {
#pragma unroll
        for (int j = 0; j < 8; j++) acc[i][j] = fmaf(a[i], b[j], acc[i][j]);
      }
    }
    __syncthreads();
  }
#pragma unroll
  for (int i = 0; i < 8; i++) {
    int m = m0 + ty * 8 + i;
    if (EXPERT && m >= cnt) continue;
    size_t prow = EXPERT ? ((size_t)s * prows + base + m) : ((size_t)s * M + m);
    float* orow = part + prow * Ntot + sel * Nthird;
#pragma unroll
    for (int j = 0; j < 8; j++)
      orow[n0 + tx * 8 + j] = acc[i][j];
  }
}

// ---- QKV reduce: q/k/v = part0+part1 + bias ----
__global__ __launch_bounds__(256) void k_qkvred(const float* __restrict__ part,
    const float* __restrict__ bq, const float* __restrict__ bk,
    const float* __restrict__ bv, float* __restrict__ qb,
    float* __restrict__ kb, float* __restrict__ vb) {
  int t = blockIdx.x;
  for (int c = threadIdx.x; c < 2304; c += 256) {
    float v = part[(size_t)t * 2304 + c] + part[((size_t)TT + t) * 2304 + c];
    if (c < 768)       qb[(size_t)t * DD + c] = v + bq[c];
    else if (c < 1536) kb[(size_t)t * DD + c - 768] = v + bk[c - 768];
    else               vb[(size_t)t * DD + c - 1536] = v + bv[c - 1536];
  }
}

// ---- O-proj reduce: x += sum(part[0..3]) + bo ----
__global__ __launch_bounds__(256) void k_ored(const float* __restrict__ part,
    const float* __restrict__ bo, float* __restrict__ x) {
  int t = blockIdx.x;
  for (int d = threadIdx.x; d < DD; d += 256) {
    float v = part[(size_t)t * DD + d]
            + part[((size_t)TT + t) * DD + d]
            + part[((size_t)2 * TT + t) * DD + d]
            + part[((size_t)3 * TT + t) * DD + d];
    x[(size_t)t * DD + d] += v + bo[d];
  }
}

// ---- expert2 reduce + gate-weighted scatter: x += w*(sum(part)+b2) ----
__global__ __launch_bounds__(256) void k_e2red(const float* __restrict__ part,
    const int* __restrict__ rows, const int* __restrict__ tidx,
    const float* __restrict__ tw, const float* __restrict__ b2,
    float* __restrict__ x) {
  int t = blockIdx.x;
  int r0 = rows[t * 2], r1 = rows[t * 2 + 1];
  int e0 = tidx[t * 2], e1 = tidx[t * 2 + 1];
  float w0 = tw[t * 2], w1 = tw[t * 2 + 1];
  for (int d = threadIdx.x; d < DD; d += 256) {
    float v0 = part[(size_t)r0 * DD + d]
             + part[((size_t)4096 + r0) * DD + d]
             + part[((size_t)8192 + r0) * DD + d]
             + part[((size_t)12288 + r0) * DD + d] + b2[e0 * DD + d];
    float v1 = part[(size_t)r1 * DD + d]
             + part[((size_t)4096 + r1) * DD + d]
             + part[((size_t)8192 + r1) * DD + d]
             + part[((size_t)12288 + r1) * DD + d] + b2[e1 * DD + d];
    x[(size_t)t * DD + d] += w0 * v0 + w1 * v1;
  }
}

// ---------------- attention (f32, separate q/k/v) ----------------
__global__ __launch_bounds__(256) void k_attn(const float* __restrict__ q,
    const float* __restrict__ k, const float* __restrict__ v, float* __restrict__ ao) {
  int b = blockIdx.z, hh = blockIdx.y, q0 = blockIdx.x * QBLK;
  __shared__ float qs[QBLK][64];
  __shared__ float sc[QBLK][SS];
  __shared__ float red[QBLK][8];
  int tid = threadIdx.x;
  const size_t hoff = (size_t)b * SS * DD + (size_t)hh * 64;
  for (int i = tid; i < QBLK * 64; i += 256) {
    int qi = i >> 6, d = i & 63;
    qs[qi][d] = q[hoff + (size_t)(q0 + qi) * DD + d];
  }
  __syncthreads();
  int kmax = q0 + QBLK;
  for (int j = tid; j < kmax; j += 256) {
    const float* kr = k + hoff + (size_t)j * DD;
    float p[QBLK];
#pragma unroll
    for (int qi = 0; qi < QBLK; qi++) p[qi] = 0.f;
#pragma unroll 4
    for (int c = 0; c < 16; c++) {
      float4 kv = *(const float4*)(kr + c * 4);
#pragma unroll
      for (int qi = 0; qi < QBLK; qi++)
        p[qi] += qs[qi][c * 4] * kv.x + qs[qi][c * 4 + 1] * kv.y +
                 qs[qi][c * 4 + 2] * kv.z + qs[qi][c * 4 + 3] * kv.w;
    }
#pragma unroll
    for (int qi = 0; qi < QBLK; qi++)
      sc[qi][j] = (j <= q0 + qi) ? p[qi] * 0.125f : -1e30f;
  }
  __syncthreads();
  int wid = tid >> 6, lane = tid & 63;
#pragma unroll
  for (int qi = 0; qi < QBLK; qi++) {
    float mx = -1e30f;
    for (int j = tid; j < kmax; j += 256) mx = fmaxf(mx, sc[qi][j]);
    for (int off = 32; off > 0; off >>= 1) mx = fmaxf(mx, __shfl_down(mx, off, 64));
    if (lane == 0) red[qi][wid] = mx;
  }
  __syncthreads();
#pragma unroll
  for (int qi = 0; qi < QBLK; qi++) {
    float mx = fmaxf(fmaxf(red[qi][0], red[qi][1]), fmaxf(red[qi][2], red[qi][3]));
    float s = 0.f;
    for (int j = tid; j < kmax; j += 256) {
      float e = __expf(sc[qi][j] - mx);
      sc[qi][j] = e;
      s += e;
    }
    for (int off = 32; off > 0; off >>= 1) s += __shfl_down(s, off, 64);
    if (lane == 0) red[qi][4 + wid] = s;
  }
  __syncthreads();
  int d = tid & 63, g = tid >> 6;
  for (int qi = g; qi < QBLK; qi += 4) {
    float inv = 1.f / (red[qi][4] + red[qi][5] + red[qi][6] + red[qi][7]);
    float acc = 0.f;
    int jend = q0 + qi + 1;
    const float* vp = v + hoff + d;
    for (int j = 0; j < jend; j++) acc = fmaf(sc[qi][j], vp[(size_t)j * DD], acc);
    ao[hoff + (size_t)(q0 + qi) * DD + d] = acc * inv;
  }
}

// ---------------- gate logits ----------------
__global__ __launch_bounds__(256) void k_gate(const float* __restrict__ h,
    const float* __restrict__ gw, const float* __restrict__ gb,
    float* __restrict__ glog) {
  __shared__ float hr[DD];
  int t = blockIdx.x;
  for (int d = threadIdx.x; d < DD; d += 256) hr[d] = h[(size_t)t * DD + d];
  __syncthreads();
  int e = threadIdx.x >> 5, j = threadIdx.x & 31;
  float s = 0.f;
  for (int d = j; d < DD; d += 32) s += hr[d] * gw[d * EE + e];
  for (int off = 16; off > 0; off >>= 1) s += __shfl_down(s, off, 32);
  if (j == 0) glog[t * EE + e] = s + gb[e];
}

// ---------------- router ----------------
__global__ void k_zero(int* counts, int* cursor) {
  int i = threadIdx.x;
  if (i < EE) { counts[i] = 0; cursor[i] = 0; }
}

__global__ void k_router(const float* __restrict__ glog, int* __restrict__ tidx,
    float* __restrict__ tw, int* __restrict__ counts) {
  int t = blockIdx.x * 256 + threadIdx.x;
  if (t >= TT) return;
  float l[EE];
#pragma unroll
  for (int e = 0; e < EE; e++) l[e] = glog[t * EE + e];
  int i0 = 0; float v0 = l[0];
#pragma unroll
  for (int e = 1; e < EE; e++) if (l[e] > v0) { v0 = l[e]; i0 = e; }
  int i1 = -1; float v1 = -1e30f;
#pragma unroll
  for (int e = 0; e < EE; e++) if (e != i0 && l[e] > v1) { v1 = l[e]; i1 = e; }
  float e1 = __expf(v1 - v0);
  float inv = 1.f / (1.f + e1);
  tw[t * 2] = inv; tw[t * 2 + 1] = e1 * inv;
  tidx[t * 2] = i0; tidx[t * 2 + 1] = i1;
  atomicAdd(&counts[i0], 1);
  atomicAdd(&counts[i1], 1);
}

__global__ void k_scan(const int* __restrict__ counts, int* __restrict__ bases,
                       int* __restrict__ cursor) {
  int b = 0;
  for (int e = 0; e < EE; e++) { bases[e] = b; cursor[e] = b; b += counts[e]; }
}

__global__ void k_assign(const int* __restrict__ tidx, int* __restrict__ cursor,
                         int* __restrict__ rows, int* __restrict__ gtok) {
  int t = blockIdx.x * 256 + threadIdx.x;
  if (t >= TT) return;
#pragma unroll
  for (int kk = 0; kk < 2; kk++) {
    int e = tidx[t * 2 + kk];
    int r = atomicAdd(&cursor[e], 1);
    rows[t * 2 + kk] = r;
    gtok[r] = t;
  }
}

// ------- f32 expert FFN1, k-major A + b128 reads (feeds router) -------
__global__ __launch_bounds__(256) void k_expert1(const float* __restrict__ h,
    const float* __restrict__ w1, const float* __restrict__ b1,
    const int* __restrict__ gtok, const int* __restrict__ counts,
    const int* __restrict__ bases, float* __restrict__ gh1) {
  int e = blockIdx.z;
  int cnt = counts[e];
  int m0 = blockIdx.y * 128;
  if (m0 >= cnt) return;
  int base = bases[e];
  int n0 = blockIdx.x * 128;
  const float* W = w1 + (size_t)e * DD * FF;
  __shared__ float As[16][132];   // k-major
  __shared__ float Bs[16][132];
  int tid = threadIdx.x;
  int tx = tid & 15, ty = tid >> 4;
  int ra = tid >> 1, ka0 = (tid & 1) * 8;
  int kb = tid >> 4, nb0 = (tid & 15) * 8;
  int tok = (m0 + ra < cnt) ? gtok[base + m0 + ra] : -1;
  const float* Arow = h + (size_t)(tok < 0 ? 0 : tok) * DD;
  float acc[8][8] = {};
  for (int k0 = 0; k0 < DD; k0 += 16) {
    float4 av0 = make_float4(0.f, 0.f, 0.f, 0.f), av1 = av0;
    if (tok >= 0) {
      av0 = *(const float4*)(Arow + k0 + ka0);
      av1 = *(const float4*)(Arow + k0 + ka0 + 4);
    }
    As[ka0 + 0][ra] = av0.x; As[ka0 + 1][ra] = av0.y;
    As[ka0 + 2][ra] = av0.z; As[ka0 + 3][ra] = av0.w;
    As[ka0 + 4][ra] = av1.x; As[ka0 + 5][ra] = av1.y;
    As[ka0 + 6][ra] = av1.z; As[ka0 + 7][ra] = av1.w;
    const float* Wrow = W + (size_t)(k0 + kb) * FF + n0 + nb0;
    *(float4*)&Bs[kb][nb0] = *(const float4*)(Wrow);
    *(float4*)&Bs[kb][nb0 + 4] = *(const float4*)(Wrow + 4);
    __syncthreads();
#pragma unroll
    for (int kk = 0; kk < 16; kk++) {
      float4 a0 = *(const float4*)&As[kk][ty * 8];
      float4 a1 = *(const float4*)&As[kk][ty * 8 + 4];
      float4 b0 = *(const float4*)&Bs[kk][tx * 8];
      float4 b1 = *(const float4*)&Bs[kk][tx * 8 + 4];
      float a[8] = {a0.x, a0.y, a0.z, a0.w, a1.x, a1.y, a1.z, a1.w};
      float b[8] = {b0.x, b0.y, b0.z, b0.w, b1.x, b1.y, b1.z, b1.w};
#pragma unroll
      for (int i = 0; i < 8; i++) {
#pragma unroll
        for (int j = 0; j < 8; j++) acc[i][j] = fmaf(a[i], b[j], acc[i][j]);
      }
    }
    __syncthreads();
  }
#pragma unroll
  for (int i = 0; i < 8; i++) {
    int m = m0 + ty * 8 + i;
    if (m >= cnt) continue;
    float* orow = gh1 + (size_t)(base + m) * FF;
#pragma unroll
    for (int j = 0; j < 8; j++) {
      int n = n0 + tx * 8 + j;
      float vv = acc[i][j] + b1[e * FF + n];
      orow[n] = 0.5f * vv * (1.f + erff(vv * 0.70710678118654752f));
    }
  }
}

// =============== bf16 MFMA GEMM (routing-irrelevant work only) ===============
// EPI: 0 = store f32 (+bias), 2 = gelu -> bf16 (+bias). BF32: stage B from f32.
template<bool EXPERT, bool GATHER, bool BIAS, int EPI, bool BF32>
__global__ __launch_bounds__(256) void k_mfma(
    const unsigned short* __restrict__ A, const void* __restrict__ Bt,
    const float* __restrict__ bias, void* __restrict__ Cv,
    int M, int N, int K,
    const int* __restrict__ gtok, const int* __restrict__ counts,
    const int* __restrict__ bases) {
  int cnt = M, base = 0;
  if (EXPERT) {
    int e = blockIdx.z;
    cnt = counts[e]; base = bases[e];
    if (BIAS) bias += (size_t)e * N;
  }
  int m0 = blockIdx.y * 128;
  if (EXPERT && m0 >= cnt) return;
  int n0 = blockIdx.x * 128;

  __shared__ unsigned short As[128 * 40];
  __shared__ unsigned short Bs[128 * 40];

  int tid = threadIdx.x;
  int srow = tid >> 1;            // 0..127
  int scol = (tid & 1) * 16;      // 0 or 16 (elements)

  bool avalid = true;
  const unsigned short* arow;
  if (GATHER) {
    avalid = (m0 + srow) < cnt;
    int tk = avalid ? gtok[base + m0 + srow] : 0;
    arow = A + (size_t)tk * K + scol;
  } else if (EXPERT) {
    avalid = (m0 + srow) < cnt;
    arow = A + (size_t)(base + m0 + (avalid ? srow : 0)) * K + scol;
  } else {
    arow = A + (size_t)(m0 + srow) * K + scol;
  }

  const unsigned short* brow16 = nullptr;
  const float* browf = nullptr;
  if (BF32) {
    browf = (const float*)Bt + (size_t)(n0 + srow) * K + scol;
  } else {
    const unsigned short* B16 = (const unsigned short*)Bt;
    if (EXPERT) B16 += (size_t)blockIdx.z * N * K;
    brow16 = B16 + (size_t)(n0 + srow) * K + scol;
  }

  unsigned short* As_w = As + srow * 40 + scol;
  unsigned short* Bs_w = Bs + srow * 40 + scol;

  int lane = tid & 63, wid = tid >> 6;
  int wr = wid >> 1, wc = wid & 1;
  int l15 = lane & 15, lg = lane >> 4;
  const unsigned short* Ar = As + ((wr * 64 + l15) * 40 + lg * 8);
  const unsigned short* Br = Bs + ((wc * 64 + l15) * 40 + lg * 8);

  f32x4 acc[4][4];
#pragma unroll
  for (int i = 0; i < 4; i++)
#pragma unroll
    for (int j = 0; j < 4; j++) acc[i][j] = (f32x4){0.f, 0.f, 0.f, 0.f};

  for (int k0 = 0; k0 < K; k0 += 32) {
    uint4 av0 = {0, 0, 0, 0}, av1 = {0, 0, 0, 0};
    if (avalid) {
      av0 = *(const uint4*)(arow + k0);
      av1 = *(const uint4*)(arow + k0 + 8);
    }
    uint4 bv0, bv1;
    if (BF32) {
      float4 f0 = *(const float4*)(browf + k0);
      float4 f1 = *(const float4*)(browf + k0 + 4);
      float4 f2 = *(const float4*)(browf + k0 + 8);
      float4 f3 = *(const float4*)(browf + k0 + 12);
      bv0 = make_uint4(pk2(f0.x, f0.y), pk2(f0.z, f0.w), pk2(f1.x, f1.y), pk2(f1.z, f1.w));
      bv1 = make_uint4(pk2(f2.x, f2.y), pk2(f2.z, f2.w), pk2(f3.x, f3.y), pk2(f3.z, f3.w));
    } else {
      bv0 = *(const uint4*)(brow16 + k0);
      bv1 = *(const uint4*)(brow16 + k0 + 8);
    }
    *(uint4*)As_w = av0; *(uint4*)(As_w + 8) = av1;
    *(uint4*)Bs_w = bv0; *(uint4*)(Bs_w + 8) = bv1;
    __syncthreads();
    bf16x8 af[4], bfr[4];
#pragma unroll
    for (int f = 0; f < 4; f++) {
      af[f]  = *(const bf16x8*)(Ar + f * 640);
      bfr[f] = *(const bf16x8*)(Br + f * 640);
    }
#pragma unroll
    for (int i = 0; i < 4; i++)
#pragma unroll
      for (int j = 0; j < 4; j++)
        acc[i][j] = __builtin_amdgcn_mfma_f32_16x16x32_bf16(af[i], bfr[j], acc[i][j], 0, 0, 0);
    __syncthreads();
  }

#pragma unroll
  for (int j = 0; j < 4; j++) {
    int n = n0 + wc * 64 + j * 16 + l15;
    float bb = BIAS ? bias[n] : 0.f;
#pragma unroll
    for (int i = 0; i < 4; i++) {
      int mb = m0 + wr * 64 + i * 16 + lg * 4;
#pragma unroll
      for (int r = 0; r < 4; r++) {
        int m = mb + r;
        if (EXPERT && m >= cnt) continue;
        size_t off = (size_t)(base + m) * N + n;
        float v = acc[i][j][r] + bb;
        if (EPI == 0) {
          ((float*)Cv)[off] = v;
        } else {
          float g = 0.5f * v * (1.f + erff(v * 0.70710678118654752f));
          ((unsigned short*)Cv)[off] = f2b(g);
        }
      }
    }
  }
}

// ---------------- MoE scatter (bf16 path): x += w0*go[r0] + w1*go[r1] ----------------
__global__ __launch_bounds__(256) void k_scatter(const float* __restrict__ go,
    const int* __restrict__ rows, const float* __restrict__ tw, float* __restrict__ x) {
  int t = blockIdx.x;
  int r0 = rows[t * 2], r1 = rows[t * 2 + 1];
  float w0 = tw[t * 2], w1 = tw[t * 2 + 1];
  float* xr = x + (size_t)t * DD;
  const float* g0 = go + (size_t)r0 * DD;
  const float* g1 = go + (size_t)r1 * DD;
  for (int d = threadIdx.x; d < DD; d += 256)
    xr[d] += w0 * g0[d] + w1 * g1[d];
}

// ================= host =================
extern "C" void kernel_launch(void* const* d_in, const int* in_sizes, int n_in,
                              void* d_out, int out_size, void* d_ws, size_t ws_size,
                              hipStream_t stream) {
  (void)in_sizes; (void)n_in; (void)out_size;
  const int* tok   = (const int*)d_in[0];
  const float* emb = (const float*)d_in[1];
  const float* pos = (const float*)d_in[2];
  const float* wq  = (const float*)d_in[3];
  const float* bq  = (const float*)d_in[4];
  const float* wk  = (const float*)d_in[5];
  const float* bk  = (const float*)d_in[6];
  const float* wv  = (const float*)d_in[7];
  const float* bvv = (const float*)d_in[8];
  const float* wo  = (const float*)d_in[9];
  const float* bo  = (const float*)d_in[10];
  const float* ln1 = (const float*)d_in[11];
  const float* ln2 = (const float*)d_in[12];
  const float* gw  = (const float*)d_in[13];
  const float* gb  = (const float*)d_in[14];
  const float* w1  = (const float*)d_in[15];
  const float* b1  = (const float*)d_in[16];
  const float* w2  = (const float*)d_in[17];
  const float* b2  = (const float*)d_in[18];
  const float* lnf = (const float*)d_in[19];

  // ---- scratch carved from d_out (65.5M f32; all dead before lm_head) ----
  float* fp = (float*)d_out;
  float* qb   = fp; fp += (size_t)TT * DD;
  float* kb   = fp; fp += (size_t)TT * DD;
  float* vb   = fp; fp += (size_t)TT * DD;
  float* ao   = fp; fp += (size_t)TT * DD;
  float* x    = fp; fp += (size_t)TT * DD;
  float* h    = fp; fp += (size_t)TT * DD;
  float* gh1  = fp; fp += (size_t)TT * 2 * FF;      // f32, layer-1 experts
  float* go   = fp; fp += (size_t)TT * 2 * DD;
  float* glog = fp; fp += (size_t)TT * EE;
  float* tw   = fp; fp += (size_t)TT * 2;
  int* tidx   = (int*)fp; fp += TT * 2;
  int* rows   = (int*)fp; fp += TT * 2;
  int* gtok   = (int*)fp; fp += TT * 2;
  int* counts = (int*)fp; fp += 16;
  int* cursor = (int*)fp; fp += 16;
  int* bases  = (int*)fp; fp += 16;
  unsigned short* hb   = (unsigned short*)fp; fp += (size_t)TT * DD / 2;
  unsigned short* gh1b = (unsigned short*)fp; fp += (size_t)TT * 2 * FF / 2;
  unsigned short* w1t  = (unsigned short*)fp; fp += (size_t)EE * DD * FF / 2;  // layer-2 only
  unsigned short* w2t  = (unsigned short*)fp; fp += (size_t)EE * FF * DD / 2;
  float* part = fp; fp += (size_t)4 * 4096 * DD;    // split-K partials, 12.58M
  // total ~63.8M floats < 65.5M

  // d_ws: hf (bf16 final activations, must survive lm_head) + optional embT
  unsigned short* hf = (unsigned short*)d_ws;
  unsigned short* embT = (unsigned short*)d_ws + (size_t)TT * DD;
  bool useEmbT = ws_size >= (size_t)TT * DD * 2 + (size_t)VV * DD * 2;

  // ---- pre-pass ----
  k_embed<<<TT, 256, 0, stream>>>(tok, emb, pos, x);
  k_tcvt<<<dim3(96, 24, EE), 256, 0, stream>>>(w1 + (size_t)1 * EE * DD * FF, w1t,
      DD, FF, (size_t)DD * FF, (size_t)DD * FF);
  k_tcvt<<<dim3(24, 96, EE), 256, 0, stream>>>(w2 + (size_t)1 * EE * FF * DD, w2t,
      FF, DD, (size_t)FF * DD, (size_t)FF * DD);
  if (useEmbT)
    k_cvt<<<(VV * DD) / (256 * 8), 256, 0, stream>>>(emb, embT);

  for (int l = 0; l < NLAYER; l++) {
    const float* wq_l = wq + (size_t)l * DD * DD;
    const float* wk_l = wk + (size_t)l * DD * DD;
    const float* wv_l = wv + (size_t)l * DD * DD;
    const float* wo_l = wo + (size_t)l * DD * DD;

    // attention block (f32 — feeds routers)
    k_rmsnorm<<<TT, 256, 0, stream>>>(x, ln1 + (size_t)l * DD, h, hb);
    // QKV: split-K=2, 3 column-thirds
    k_skf32<false><<<dim3(18, 16, 2), 256, 0, stream>>>(h, wq_l, wk_l, wv_l,
        part, TT, 2304, 768, 768, 384, 2, TT, nullptr, nullptr);
    k_qkvred<<<TT, 256, 0, stream>>>(part, bq + (size_t)l * DD, bk + (size_t)l * DD,
        bvv + (size_t)l * DD, qb, kb, vb);
    k_attn<<<dim3(SS / QBLK, HH, BB), 256, 0, stream>>>(qb, kb, vb, ao);
    // O-proj: split-K=4
    k_skf32<false><<<dim3(6, 16, 4), 256, 0, stream>>>(ao, wo_l, wo_l, wo_l,
        part, TT, 768, 768, 768, 192, 4, TT, nullptr, nullptr);
    k_ored<<<TT, 256, 0, stream>>>(part, bo + (size_t)l * DD, x);

    // MoE block
    k_rmsnorm<<<TT, 256, 0, stream>>>(x, ln2 + (size_t)l * DD, h, hb);
    k_gate<<<TT, 256, 0, stream>>>(h, gw + (size_t)l * DD * EE, gb + (size_t)l * EE, glog);
    k_zero<<<1, 64, 0, stream>>>(counts, cursor);
    k_router<<<TT / 256, 256, 0, stream>>>(glog, tidx, tw, counts);
    k_scan<<<1, 1, 0, stream>>>(counts, bases, cursor);
    k_assign<<<TT / 256, 256, 0, stream>>>(tidx, cursor, rows, gtok);
    if (l < NLAYER - 1) {
      // feeds next layer's router -> f32 experts
      k_expert1<<<dim3(FF / 128, TT / 128, EE), 256, 0, stream>>>(
          h, w1 + (size_t)l * EE * DD * FF, b1 + (size_t)l * EE * FF,
          gtok, counts, bases, gh1);
      // expert2: split-K=4 over K=FF, then fused reduce+scatter
      k_skf32<true><<<dim3(6, 16, 32), 256, 0, stream>>>(gh1,
          w2 + (size_t)l * EE * FF * DD, nullptr, nullptr,
          part, TT, 768, 768, FF, 768, 4, 4096, counts, bases);
      k_e2red<<<TT, 256, 0, stream>>>(part, rows, tidx, tw,
          b2 + (size_t)l * EE * DD, x);
    } else {
      // last layer: routing-irrelevant -> bf16 MFMA
      k_mfma<true, true, true, 2, false><<<dim3(FF / 128, TT / 128, EE), 256, 0, stream>>>(
          hb, w1t, b1 + (size_t)l * EE * FF, gh1b,
          TT, FF, DD, gtok, counts, bases);
      k_mfma<true, false, true, 0, false><<<dim3(DD / 128, TT / 128, EE), 256, 0, stream>>>(
          gh1b, w2t, b2 + (size_t)l * EE * DD, go,
          TT, DD, FF, gtok, counts, bases);
      k_scatter<<<TT, 256, 0, stream>>>(go, rows, tw, x);
    }
  }

  // final norm + lm_head (bf16 MFMA)
  k_rmsnorm<<<TT, 256, 0, stream>>>(x, lnf, h, hf);
  if (useEmbT) {
    k_mfma<false, false, false, 0, false><<<dim3(VV / 128, TT / 128), 256, 0, stream>>>(
        hf, embT, nullptr, (float*)d_out,
        TT, VV, DD, nullptr, nullptr, nullptr);
  } else {
    k_mfma<false, false, false, 0, true><<<dim3(VV / 128, TT / 128), 256, 0, stream>>>(
        hf, emb, nullptr, (float*)d_out,
        TT, VV, DD, nullptr, nullptr, nullptr);
  }
}